// Round 5
// baseline (7329.626 us; speedup 1.0000x reference)
//
#include <hip/hip_runtime.h>
#include <math.h>

typedef float vf4 __attribute__((ext_vector_type(4)));
typedef _Float16 f16;
typedef _Float16 f16x8 __attribute__((ext_vector_type(8)));
typedef _Float16 f16x4 __attribute__((ext_vector_type(4)));
typedef float f32x4 __attribute__((ext_vector_type(4)));

static constexpr int Ncnt = 32768;
static constexpr int Kcb  = 4096;
static constexpr int Dim  = 256;

static constexpr float EPSf  = 1e-5f;
static constexpr float KEPSf = (float)(4096.0 * 1e-5);

// d_out float offsets (reference return order, flattened)
static constexpr size_t OQ  = 0;
static constexpr size_t OI  = (size_t)Ncnt * Dim;
static constexpr size_t OL  = OI + Ncnt;
static constexpr size_t OE  = OL + 1;
static constexpr size_t OCS = OE + (size_t)Kcb * Dim;
static constexpr size_t OW  = OCS + Kcb;
static constexpr size_t OU  = OW + (size_t)Kcb * Dim;
static constexpr size_t OS  = OU + Kcb;
static constexpr size_t OR  = OS + Kcb;

// async global->LDS, 16B per lane; LDS dest is wave-uniform base + lane*16
#define GLD16(gp, lp)                                                   \
  __builtin_amdgcn_global_load_lds(                                     \
      (const __attribute__((address_space(1))) void*)(gp),              \
      (__attribute__((address_space(3))) void*)(lp), 16, 0, 0)

// ---------------------------------------------------------------------------
// numpy pairwise_sum over fl(p[i]*p[i]) for n=256 (bit-exact np.sum(x*x,1))
__device__ __forceinline__ float np_sq256(const float* __restrict__ p) {
  float tot[2];
  #pragma unroll
  for (int h = 0; h < 2; ++h) {
    const float* a = p + h * 128;
    float r[8];
    #pragma unroll
    for (int j = 0; j < 8; ++j) r[j] = __fmul_rn(a[j], a[j]);
    for (int i = 8; i < 128; i += 8)
      #pragma unroll
      for (int j = 0; j < 8; ++j) r[j] = __fadd_rn(r[j], __fmul_rn(a[i + j], a[i + j]));
    tot[h] = __fadd_rn(__fadd_rn(__fadd_rn(r[0], r[1]), __fadd_rn(r[2], r[3])),
                       __fadd_rn(__fadd_rn(r[4], r[5]), __fadd_rn(r[6], r[7])));
  }
  return __fadd_rn(tot[0], tot[1]);
}

__global__ void rowsq_np(const float* __restrict__ E, float* __restrict__ e2, int rows) {
  const int k = blockIdx.x * 256 + threadIdx.x;
  if (k < rows) e2[k] = np_sq256(E + (size_t)k * Dim);
}

// ---------------------------------------------------------------------------
// 2-limb f16 split with exact power-of-2 scaling:
//   t = v*scale (exact); hi = f16(t); lo = f16(t - hi)  (t - (f32)hi exact)
// layout: dst row = [hi(256) | lo(256)]
__global__ void split_rows(const float* __restrict__ src, f16* __restrict__ dst,
                           const float scale, const int rows)
{
  const int i   = blockIdx.x * 256 + threadIdx.x;
  const int row = i >> 6;
  const int d0  = (i & 63) * 4;
  if (row >= rows) return;
  const vf4 v = *(const vf4*)(src + (size_t)row * 256 + d0);
  f16x4 hi, lo;
  #pragma unroll
  for (int j = 0; j < 4; ++j) {
    const float t = __fmul_rn(v[j], scale);
    const f16 h   = (f16)t;
    const float r = __fsub_rn(t, (float)h);
    hi[j] = h;
    lo[j] = (f16)r;
  }
  *(f16x4*)(dst + (size_t)row * 512 + d0)       = hi;
  *(f16x4*)(dst + (size_t)row * 512 + 256 + d0) = lo;
}

// ---------------------------------------------------------------------------
// MFMA candidate pass. Grid: 2048 = 256 row-groups x 8 col-groups. Block =
// 128 rows x 512 cols (4 col-tiles of 128). Tile 128x128, 4 waves (2x2 of
// 64x64), BK=32. Virtual K = 768 as 3 segments of 8 steps:
//   seg0: A off 0   B off 0    (hiX*hiE)
//   seg1: A off 256 B off 0    (loX*hiE)
//   seg2: A off 0   B off 256  (hiX*loE)
// Staging: global_load_lds width=16 into DOUBLE-BUFFERED LDS; one barrier
// per step (T3 2-phase recipe): stage(st+1)->buf[nxt] issued at step top,
// ds_read+MFMA on buf[cur] cover its latency, single __syncthreads at step
// end (its vmcnt(0)/lgkmcnt(0) drain protects both buffers).
// LDS dest is linear (lane l -> base+l*16); global source chunk pre-swizzled
//   chunk = (l&3) ^ ((l>>3)&3)  ==  slot ^ ((row>>1)&3)
// so frag reads use slot ks = (kc ^ ((lc>>1)&3))*8 (proven involution).
// Proxy t = fmaf(-two_scale, acc, e2[col]) (x2 row-constant: rank-equal).
// Per-thread-slot 2-deep (t,idx); 16-lane butterfly 2-deep merge; each
// wave-half (wc) writes its top-2 -> cand[row][cg][4]. Exact argmin is
// recomputed over candidates by recheck() with numpy-exact f32 semantics.
__global__ __launch_bounds__(256, 4) void mfma_argmin(
    const f16* __restrict__ Xs, const f16* __restrict__ Es,
    const float* __restrict__ e2, const float two_scale,
    int* __restrict__ cand)
{
  __shared__ __align__(16) f16 As[2][128 * 32];
  __shared__ __align__(16) f16 Bs[2][128 * 32];

  const int tid  = threadIdx.x;
  const int bid  = blockIdx.x;
  const int row0 = (bid >> 3) * 128;
  const int cg   = bid & 7;
  const int colbase = cg * 512;

  const int l  = tid & 63;
  const int wv = tid >> 6;
  const int wr = wv >> 1;
  const int wc = wv & 1;
  const int lc = l & 15;
  const int kc = l >> 4;

  // staging: wave wv stages rows [wv*32, wv*32+16) (issue0) and +16 (issue1)
  const int srow = wv * 32 + (l >> 2);
  const int chs  = (l & 3) ^ ((l >> 3) & 3);

  const f16* aB0 = Xs + (size_t)(row0 + srow) * 512 + chs * 8;
  const f16* aB1 = aB0 + 16 * 512;

  // frag-read swizzled k-slot (row = ..+lc; (row>>1)&3 == (lc>>1)&3)
  const int ks = (kc ^ ((lc >> 1) & 3)) * 8;

  const float nts = -two_scale;

  float t1[16], t2[16];
  int   i1[16], i2[16];
  #pragma unroll
  for (int s = 0; s < 16; ++s) {
    t1[s] = INFINITY; t2[s] = INFINITY; i1[s] = 0x7fffffff; i2[s] = 0x7fffffff;
  }

  #pragma unroll 1
  for (int ct = 0; ct < 4; ++ct) {
    const f16* bB0 = Es + (size_t)(colbase + ct * 128 + srow) * 512 + chs * 8;
    const f16* bB1 = bB0 + 16 * 512;

    f32x4 acc[4][4];
    #pragma unroll
    for (int i = 0; i < 4; ++i)
      #pragma unroll
      for (int j = 0; j < 4; ++j)
        acc[i][j] = (f32x4){0.0f, 0.0f, 0.0f, 0.0f};

    // prologue: stage step 0 into buffer 0 (prior reads of buf0 were
    // protected by the previous step's end-of-step barrier)
    GLD16(aB0, &As[0][wv * 1024]); GLD16(aB1, &As[0][wv * 1024 + 512]);
    GLD16(bB0, &Bs[0][wv * 1024]); GLD16(bB1, &Bs[0][wv * 1024 + 512]);
    __syncthreads();                      // step-0 tile visible

    #pragma unroll
    for (int st = 0; st < 24; ++st) {
      const int cur = st & 1;
      const int nxt = cur ^ 1;

      if (st + 1 < 24) {                  // issue next stage FIRST (latency
        const int sn = st + 1;            // flies under ds_read + MFMA)
        const int aO = ((sn >> 3) == 1 ? 256 : 0) + (sn & 7) * 32;  // constexpr
        const int bO = ((sn >> 3) == 2 ? 256 : 0) + (sn & 7) * 32;  // constexpr
        GLD16(aB0 + aO, &As[nxt][wv * 1024]);
        GLD16(aB1 + aO, &As[nxt][wv * 1024 + 512]);
        GLD16(bB0 + bO, &Bs[nxt][wv * 1024]);
        GLD16(bB1 + bO, &Bs[nxt][wv * 1024 + 512]);
      }

      f16x8 af[4], bf[4];
      #pragma unroll
      for (int f = 0; f < 4; ++f) {
        af[f] = *(const f16x8*)(&As[cur][(wr * 64 + f * 16 + lc) * 32 + ks]);
        bf[f] = *(const f16x8*)(&Bs[cur][(wc * 64 + f * 16 + lc) * 32 + ks]);
      }

      #pragma unroll
      for (int fm = 0; fm < 4; ++fm)
        #pragma unroll
        for (int fn = 0; fn < 4; ++fn)
          acc[fm][fn] = __builtin_amdgcn_mfma_f32_16x16x32_f16(
              af[fm], bf[fn], acc[fm][fn], 0, 0, 0);

      __syncthreads();                    // ONE barrier/step: drains vmcnt
                                          // (stage st+1 done) + lgkm (reads
                                          // of buf[cur] done by all waves)
    }

    // fold this col-tile: 2-deep insert, cols strictly ascending over ct,fn
    float e2v[4];
    #pragma unroll
    for (int fn = 0; fn < 4; ++fn)
      e2v[fn] = e2[colbase + ct * 128 + wc * 64 + fn * 16 + lc];

    #pragma unroll
    for (int fm = 0; fm < 4; ++fm) {
      #pragma unroll
      for (int j = 0; j < 4; ++j) {
        const int s = fm * 4 + j;
        #pragma unroll
        for (int fn = 0; fn < 4; ++fn) {
          const int col = colbase + ct * 128 + wc * 64 + fn * 16 + lc;
          const float t = fmaf(nts, acc[fm][fn][j], e2v[fn]);
          if (t < t1[s]) {
            t2[s] = t1[s]; i2[s] = i1[s]; t1[s] = t; i1[s] = col;
          } else if (t < t2[s]) {
            t2[s] = t; i2[s] = col;
          }
        }
      }
    }
  }

  // 16-lane butterfly 2-deep merge within each kc row-group (lexicographic)
  #pragma unroll
  for (int s = 0; s < 16; ++s) {
    #pragma unroll
    for (int m = 1; m < 16; m <<= 1) {
      const float p1 = __shfl_xor(t1[s], m);
      const float p2 = __shfl_xor(t2[s], m);
      const int   q1 = __shfl_xor(i1[s], m);
      const int   q2 = __shfl_xor(i2[s], m);
      const bool pl = (p1 < t1[s]) || (p1 == t1[s] && q1 < i1[s]);
      float n1, n2; int m1, m2;
      if (pl) {
        n1 = p1; m1 = q1;
        const bool sl = (t1[s] < p2) || (t1[s] == p2 && i1[s] < q2);
        n2 = sl ? t1[s] : p2; m2 = sl ? i1[s] : q2;
      } else {
        n1 = t1[s]; m1 = i1[s];
        const bool sl = (p1 < t2[s]) || (p1 == t2[s] && q1 < i2[s]);
        n2 = sl ? p1 : t2[s]; m2 = sl ? q1 : i2[s];
      }
      t1[s] = n1; i1[s] = m1; t2[s] = n2; i2[s] = m2;
    }
  }

  // each wave-half writes its top-2 per owned row: cand[row][cg][wc*2+{0,1}]
  if (lc == 0) {
    #pragma unroll
    for (int fm = 0; fm < 4; ++fm)
      #pragma unroll
      for (int j = 0; j < 4; ++j) {
        const int s    = fm * 4 + j;
        const int rloc = wr * 64 + fm * 16 + kc * 4 + j;
        const size_t base = ((size_t)(row0 + rloc) * 8 + cg) * 4 + wc * 2;
        cand[base]     = i1[s];
        cand[base + 1] = i2[s];
      }
  }
}

// ---------------------------------------------------------------------------
// exact recheck: for each row, recompute numpy-exact f32 distance for the 32
// candidates and take lexicographic (s, k) min — identical arithmetic to the
// previously-passing VALU kernel (serial ascending-d fmaf chain, then
// s = fl(fl(x2 - fl(2*acc)) + e2[k])), numpy first-index tie semantics.
__global__ void recheck(const float* __restrict__ X, const float* __restrict__ x2g,
                        const float* __restrict__ Eref, const float* __restrict__ e2ref,
                        const int* __restrict__ cand, int* __restrict__ idxo)
{
  __shared__ float Xl[8][256];
  const int tid  = threadIdx.x;
  const int rg   = tid >> 5;            // row within block (8 rows/block)
  const int lr   = tid & 31;            // candidate lane
  const int row0 = blockIdx.x * 8;
  const int row  = row0 + rg;

  {
    const float* xp = X + (size_t)row * 256 + lr * 8;
    *(vf4*)(&Xl[rg][lr * 8])     = *(const vf4*)xp;
    *(vf4*)(&Xl[rg][lr * 8 + 4]) = *(const vf4*)(xp + 4);
  }
  __syncthreads();

  int k = cand[(size_t)row * 32 + lr];

  float acc = 0.0f;
  const float* ep = Eref + (size_t)k * 256;
  for (int d4 = 0; d4 < 64; ++d4) {
    const vf4 xv = *(const vf4*)(&Xl[rg][d4 * 4]);
    const vf4 ev = *(const vf4*)(ep + d4 * 4);
    acc = fmaf(xv[0], ev[0], acc);
    acc = fmaf(xv[1], ev[1], acc);
    acc = fmaf(xv[2], ev[2], acc);
    acc = fmaf(xv[3], ev[3], acc);
  }
  float s = __fadd_rn(__fsub_rn(x2g[row], __fmul_rn(2.0f, acc)), e2ref[k]);

  #pragma unroll
  for (int m = 1; m < 32; m <<= 1) {
    const float os = __shfl_xor(s, m);
    const int   ok = __shfl_xor(k, m);
    if (os < s || (os == s && ok < k)) { s = os; k = ok; }
  }
  if (lr == 0) idxo[row] = k;
}

// ----------------------- counts + dw atomics + loss (no OQ/OI writes) ------
__global__ void stats_cd(const float* __restrict__ X, const float* __restrict__ E,
                         const int* __restrict__ idx, float* __restrict__ counts,
                         float* __restrict__ dw, double* __restrict__ loss_acc)
{
  __shared__ double part[4];
  const int tid  = threadIdx.x;
  const int lane = tid & 63, w = tid >> 6;
  const int row  = blockIdx.x * 4 + w;
  const int k    = idx[row];
  const vf4 xv = ((const vf4*)X)[(size_t)row * 64 + lane];
  const vf4 qv = ((const vf4*)E)[(size_t)k * 64 + lane];
  const float d0 = xv[0]-qv[0], d1 = xv[1]-qv[1], d2 = xv[2]-qv[2], d3 = xv[3]-qv[3];
  double ps = (double)(d0*d0 + d1*d1 + d2*d2 + d3*d3);
  #pragma unroll
  for (int o = 32; o; o >>= 1) ps += __shfl_down(ps, o);
  #pragma unroll
  for (int j = 0; j < 4; ++j)
    atomicAdd(dw + (size_t)k * Dim + lane * 4 + j, xv[j]);
  if (lane == 0) {
    part[w] = ps;
    atomicAdd(counts + k, 1.0f);
  }
  __syncthreads();
  if (tid == 0) atomicAdd(loss_acc, part[0] + part[1] + part[2] + part[3]);
}

// quantized gather + index write, LAST (frees OQ region for Xs during argmins)
__global__ void gather_q(const float* __restrict__ E, const int* __restrict__ idx,
                         float* __restrict__ out)
{
  const int tid  = threadIdx.x;
  const int lane = tid & 63, w = tid >> 6;
  const int row  = blockIdx.x * 4 + w;
  const int k    = idx[row];
  ((vf4*)out)[(size_t)row * 64 + lane] = ((const vf4*)E)[(size_t)k * 64 + lane];
  if (lane == 0) out[OI + row] = (float)k;
}

// ------------------------------------------------- per-code EMA scalar updates
__global__ void cs_usage(const float* __restrict__ ecs, const float* __restrict__ usage,
                         const float* __restrict__ counts, float* __restrict__ out,
                         int* __restrict__ pos_cnt)
{
  __shared__ int si[256];
  const int tid = threadIdx.x;
  const int k   = blockIdx.x * 256 + tid;
  const float cnt = counts[k];
  const float ncs = __fadd_rn(__fmul_rn(ecs[k], 0.99f), __fmul_rn(0.01f, cnt));
  out[OCS + k] = ncs;
  const float nus = __fadd_rn(__fmul_rn(usage[k], 0.99f), __fmul_rn(0.01f, cnt));
  out[OU + k] = nus;
  si[tid] = (nus > 0.0f) ? 1 : 0;
  __syncthreads();
  for (int s = 128; s; s >>= 1) {
    if (tid < s) si[tid] += si[tid + s];
    __syncthreads();
  }
  if (tid == 0) atomicAdd(pos_cnt, si[0]);
}

// n = np.sum(new_cs), numpy pairwise over 4096
__global__ void n_np_kernel(const float* __restrict__ ncs, float* __restrict__ nf) {
  __shared__ float leaf[32];
  const int t = threadIdx.x;
  if (t < 32) {
    const float* a = ncs + t * 128;
    float r[8];
    #pragma unroll
    for (int j = 0; j < 8; ++j) r[j] = a[j];
    for (int i = 8; i < 128; i += 8)
      #pragma unroll
      for (int j = 0; j < 8; ++j) r[j] = __fadd_rn(r[j], a[i + j]);
    leaf[t] = __fadd_rn(__fadd_rn(__fadd_rn(r[0], r[1]), __fadd_rn(r[2], r[3])),
                        __fadd_rn(__fadd_rn(r[4], r[5]), __fadd_rn(r[6], r[7])));
  }
  __syncthreads();
  if (t == 0) {
    float v[32];
    #pragma unroll
    for (int i = 0; i < 32; ++i) v[i] = leaf[i];
    for (int n = 32; n > 1; n >>= 1)
      for (int i = 0; i < (n >> 1); ++i) v[i] = __fadd_rn(v[2 * i], v[2 * i + 1]);
    *nf = v[0];
  }
}

// new_ema_w (in place over dw accum) and pre-embedding (written to out[OE];
// all consumers of the pre-reset embedding run before finalize_k), numpy order
__global__ void emb_pre(const float* __restrict__ emaw, float* __restrict__ out,
                        const float* __restrict__ nf)
{
  const int k = blockIdx.x;
  const int d = threadIdx.x;
  const size_t o = (size_t)k * Dim + d;
  const float dwv = out[OW + o];
  const float w = __fadd_rn(__fmul_rn(emaw[o], 0.99f), __fmul_rn(0.01f, dwv));
  out[OW + o] = w;
  const float nv  = *nf;
  const float ncs = out[OCS + k];
  const float cs  = __fmul_rn(__fdiv_rn(__fadd_rn(ncs, EPSf), __fadd_rn(nv, KEPSf)), nv);
  out[OE + o] = __fdiv_rn(w, cs);
}

__global__ void used_scatter(const int* __restrict__ idx2, int* __restrict__ used) {
  const int i = blockIdx.x * 256 + threadIdx.x;
  used[idx2[i]] = 1;
}

__global__ void finalize_k(const float* __restrict__ X, const int* __restrict__ used,
                           const int* __restrict__ steps_in, const int* __restrict__ rnd,
                           float* __restrict__ out)
{
  const int k = blockIdx.x, d = threadIdx.x;
  const int u = used[k];
  const float st = u ? 0.0f : (float)steps_in[k] + 1.0f;
  const bool dead = st > 100.0f;
  if (dead) out[OE + (size_t)k * Dim + d] = X[(size_t)rnd[k] * Dim + d];
  if (d == 0) out[OS + k] = dead ? 0.0f : st;
}

__global__ void write_scalars(const double* __restrict__ loss_acc,
                              const int* __restrict__ pos_cnt, float* __restrict__ out)
{
  if (threadIdx.x == 0) {
    out[OL] = 0.25f * (float)(*loss_acc / (double)((size_t)Ncnt * Dim));
    out[OR] = (float)(*pos_cnt) / (float)Kcb;
  }
}

// ---------------------------------------------------------------------- launch
extern "C" void kernel_launch(void* const* d_in, const int* in_sizes, int n_in,
                              void* d_out, int out_size, void* d_ws, size_t ws_size,
                              hipStream_t stream)
{
  const float* X     = (const float*)d_in[0];
  const float* E     = (const float*)d_in[1];
  const float* ECS   = (const float*)d_in[2];
  const float* EMAW  = (const float*)d_in[3];
  const float* USAGE = (const float*)d_in[4];
  const int*   STEPS = (const int*)d_in[5];
  const int*   RND   = (const int*)d_in[6];
  float* out = (float*)d_out;

  float* wsf = (float*)d_ws;
  float*  counts   = wsf;                          // [4096]  zeroed
  int*    used     = (int*)(wsf + 4096);           // [4096]  zeroed
  double* loss_acc = (double*)(wsf + 8192);        //         zeroed
  float*  nf       = wsf + 8194;
  int*    pos_cnt  = (int*)(wsf + 8195);
  const size_t ZN  = 8200;                         // zero region, floats
  float* x2g  = wsf + 8320;                        // [32768]          -> 41088
  float* e2   = wsf + 41088;                       // [4096]           -> 45184
  float* e2p  = wsf + 45184;                       // [4096]           -> 49280
  int*   idx1 = (int*)(wsf + 49280);               // [32768]          -> 82048
  int*   idx2 = (int*)(wsf + 82048);               // [32768]          -> 114816
  f16*   Es   = (f16*)(wsf + 114816);              // 4096*512 f16 = 1048576 f -> 1163392
  int*   cand = (int*)(wsf + 1163392);             // 32768*32 ints    -> 2211968
  // pre-reset embedding lives directly in out[OE] (consumers run pre-reset).
  // Xs (32768x512 f16 = 32 MiB) parks exactly in the OQ output region;
  // gather_q rewrites OQ after the second argmin is done.
  f16*   Xsp  = (f16*)out;

  hipMemsetAsync(d_ws, 0, ZN * sizeof(float), stream);
  hipMemsetAsync(out + OW, 0, (size_t)Kcb * Dim * sizeof(float), stream); // dw accum

  rowsq_np     <<<Ncnt / 256, 256, 0, stream>>>(X, x2g, Ncnt);
  rowsq_np     <<<Kcb / 256,  256, 0, stream>>>(E, e2, Kcb);
  split_rows   <<<Ncnt / 4,   256, 0, stream>>>(X, Xsp, 64.0f, Ncnt);      // 2^6
  split_rows   <<<Kcb / 4,    256, 0, stream>>>(E, Es, 16777216.0f, Kcb);  // 2^24
  mfma_argmin  <<<2048,       256, 0, stream>>>(Xsp, Es, e2, 0x1p-29f, cand);
  recheck      <<<Ncnt / 8,   256, 0, stream>>>(X, x2g, E, e2, cand, idx1);
  stats_cd     <<<Ncnt / 4,   256, 0, stream>>>(X, E, idx1, counts, out + OW, loss_acc);
  cs_usage     <<<Kcb / 256,  256, 0, stream>>>(ECS, USAGE, counts, out, pos_cnt);
  n_np_kernel  <<<1,          64,  0, stream>>>(out + OCS, nf);
  emb_pre      <<<Kcb,        256, 0, stream>>>(EMAW, out, nf);
  rowsq_np     <<<Kcb / 256,  256, 0, stream>>>(out + OE, e2p, Kcb);
  split_rows   <<<Kcb / 4,    256, 0, stream>>>(out + OE, Es, 256.0f, Kcb); // 2^8
  mfma_argmin  <<<2048,       256, 0, stream>>>(Xsp, Es, e2p, 0x1p-13f, cand);
  recheck      <<<Ncnt / 8,   256, 0, stream>>>(X, x2g, out + OE, e2p, cand, idx2);
  used_scatter <<<Ncnt / 256, 256, 0, stream>>>(idx2, used);
  finalize_k   <<<Kcb,        256, 0, stream>>>(X, used, STEPS, RND, out);
  gather_q     <<<Ncnt / 4,   256, 0, stream>>>(E, idx1, out);
  write_scalars<<<1,          64,  0, stream>>>(loss_acc, pos_cnt, out);

  (void)in_sizes; (void)n_in; (void)out_size; (void)ws_size;
}

// Round 6
// 1960.578 us; speedup vs baseline: 3.7385x; 3.7385x over previous
//
#include <hip/hip_runtime.h>
#include <math.h>

typedef float vf4 __attribute__((ext_vector_type(4)));
typedef _Float16 f16;
typedef _Float16 f16x8 __attribute__((ext_vector_type(8)));
typedef _Float16 f16x4 __attribute__((ext_vector_type(4)));
typedef float f32x4 __attribute__((ext_vector_type(4)));

static constexpr int Ncnt = 32768;
static constexpr int Kcb  = 4096;
static constexpr int Dim  = 256;

static constexpr float EPSf  = 1e-5f;
static constexpr float KEPSf = (float)(4096.0 * 1e-5);

// d_out float offsets (reference return order, flattened)
static constexpr size_t OQ  = 0;
static constexpr size_t OI  = (size_t)Ncnt * Dim;
static constexpr size_t OL  = OI + Ncnt;
static constexpr size_t OE  = OL + 1;
static constexpr size_t OCS = OE + (size_t)Kcb * Dim;
static constexpr size_t OW  = OCS + Kcb;
static constexpr size_t OU  = OW + (size_t)Kcb * Dim;
static constexpr size_t OS  = OU + Kcb;
static constexpr size_t OR  = OS + Kcb;

// async global->LDS, 16B per lane; LDS dest is wave-uniform base + lane*16
#define GLD16(gp, lp)                                                   \
  __builtin_amdgcn_global_load_lds(                                     \
      (const __attribute__((address_space(1))) void*)(gp),              \
      (__attribute__((address_space(3))) void*)(lp), 16, 0, 0)

// ---------------------------------------------------------------------------
// numpy pairwise_sum over fl(p[i]*p[i]) for n=256 (bit-exact np.sum(x*x,1))
__device__ __forceinline__ float np_sq256(const float* __restrict__ p) {
  float tot[2];
  #pragma unroll
  for (int h = 0; h < 2; ++h) {
    const float* a = p + h * 128;
    float r[8];
    #pragma unroll
    for (int j = 0; j < 8; ++j) r[j] = __fmul_rn(a[j], a[j]);
    for (int i = 8; i < 128; i += 8)
      #pragma unroll
      for (int j = 0; j < 8; ++j) r[j] = __fadd_rn(r[j], __fmul_rn(a[i + j], a[i + j]));
    tot[h] = __fadd_rn(__fadd_rn(__fadd_rn(r[0], r[1]), __fadd_rn(r[2], r[3])),
                       __fadd_rn(__fadd_rn(r[4], r[5]), __fadd_rn(r[6], r[7])));
  }
  return __fadd_rn(tot[0], tot[1]);
}

__global__ void rowsq_np(const float* __restrict__ E, float* __restrict__ e2, int rows) {
  const int k = blockIdx.x * 256 + threadIdx.x;
  if (k < rows) e2[k] = np_sq256(E + (size_t)k * Dim);
}

// ---------------------------------------------------------------------------
// 2-limb f16 split with exact power-of-2 scaling:
//   t = v*scale (exact); hi = f16(t); lo = f16(t - hi)  (t - (f32)hi exact)
// layout: dst row = [hi(256) | lo(256)]
__global__ void split_rows(const float* __restrict__ src, f16* __restrict__ dst,
                           const float scale, const int rows)
{
  const int i   = blockIdx.x * 256 + threadIdx.x;
  const int row = i >> 6;
  const int d0  = (i & 63) * 4;
  if (row >= rows) return;
  const vf4 v = *(const vf4*)(src + (size_t)row * 256 + d0);
  f16x4 hi, lo;
  #pragma unroll
  for (int j = 0; j < 4; ++j) {
    const float t = __fmul_rn(v[j], scale);
    const f16 h   = (f16)t;
    const float r = __fsub_rn(t, (float)h);
    hi[j] = h;
    lo[j] = (f16)r;
  }
  *(f16x4*)(dst + (size_t)row * 512 + d0)       = hi;
  *(f16x4*)(dst + (size_t)row * 512 + 256 + d0) = lo;
}

// ---------------------------------------------------------------------------
// MFMA candidate pass. Grid: 2048 = 256 row-groups x 8 col-groups. Block =
// 128 rows x 512 cols (4 col-tiles of 128). Tile 128x128, 4 waves (2x2 of
// 64x64), BK=32. Virtual K = 768 as 3 segments of 8 steps:
//   seg0: A off 0   B off 0    (hiX*hiE)
//   seg1: A off 256 B off 0    (loX*hiE)
//   seg2: A off 0   B off 256  (hiX*loE)
// Staging: global_load_lds width=16 into DOUBLE-BUFFERED LDS; one barrier
// per step (T3 2-phase recipe): stage(st+1)->buf[nxt] issued at step top,
// ds_read+MFMA on buf[cur] cover its latency, single __syncthreads at step
// end (its vmcnt(0)/lgkmcnt(0) drain protects both buffers).
// launch_bounds(256,2): register cap 256 on the UNIFIED VGPR+AGPR file.
// Live state ~192 (64 AGPR acc + 64 best-state + 32 frags + misc) -> fits
// with NO spill at 2 blocks/CU. (256,4) = cap 128 -> accumulator spill to
// scratch, 6 GB/dispatch scratch writes, 5x regression (round-5 lesson).
// LDS dest is linear (lane l -> base+l*16); global source chunk pre-swizzled
//   chunk = (l&3) ^ ((l>>3)&3)  ==  slot ^ ((row>>1)&3)
// so frag reads use slot ks = (kc ^ ((lc>>1)&3))*8 (proven involution).
// Proxy t = fmaf(-two_scale, acc, e2[col]) (x2 row-constant: rank-equal).
// Per-thread-slot 2-deep (t,idx); 16-lane butterfly 2-deep merge; each
// wave-half (wc) writes its top-2 -> cand[row][cg][4]. Exact argmin is
// recomputed over candidates by recheck() with numpy-exact f32 semantics.
__global__ __launch_bounds__(256, 2) void mfma_argmin(
    const f16* __restrict__ Xs, const f16* __restrict__ Es,
    const float* __restrict__ e2, const float two_scale,
    int* __restrict__ cand)
{
  __shared__ __align__(16) f16 As[2][128 * 32];
  __shared__ __align__(16) f16 Bs[2][128 * 32];

  const int tid  = threadIdx.x;
  const int bid  = blockIdx.x;
  const int row0 = (bid >> 3) * 128;
  const int cg   = bid & 7;
  const int colbase = cg * 512;

  const int l  = tid & 63;
  const int wv = tid >> 6;
  const int wr = wv >> 1;
  const int wc = wv & 1;
  const int lc = l & 15;
  const int kc = l >> 4;

  // staging: wave wv stages rows [wv*32, wv*32+16) (issue0) and +16 (issue1)
  const int srow = wv * 32 + (l >> 2);
  const int chs  = (l & 3) ^ ((l >> 3) & 3);

  const f16* aB0 = Xs + (size_t)(row0 + srow) * 512 + chs * 8;
  const f16* aB1 = aB0 + 16 * 512;

  // frag-read swizzled k-slot (row = ..+lc; (row>>1)&3 == (lc>>1)&3)
  const int ks = (kc ^ ((lc >> 1) & 3)) * 8;

  const float nts = -two_scale;

  float t1[16], t2[16];
  int   i1[16], i2[16];
  #pragma unroll
  for (int s = 0; s < 16; ++s) {
    t1[s] = INFINITY; t2[s] = INFINITY; i1[s] = 0x7fffffff; i2[s] = 0x7fffffff;
  }

  #pragma unroll 1
  for (int ct = 0; ct < 4; ++ct) {
    const f16* bB0 = Es + (size_t)(colbase + ct * 128 + srow) * 512 + chs * 8;
    const f16* bB1 = bB0 + 16 * 512;

    f32x4 acc[4][4];
    #pragma unroll
    for (int i = 0; i < 4; ++i)
      #pragma unroll
      for (int j = 0; j < 4; ++j)
        acc[i][j] = (f32x4){0.0f, 0.0f, 0.0f, 0.0f};

    // prologue: stage step 0 into buffer 0 (prior reads of buf0 were
    // protected by the previous step's end-of-step barrier)
    GLD16(aB0, &As[0][wv * 1024]); GLD16(aB1, &As[0][wv * 1024 + 512]);
    GLD16(bB0, &Bs[0][wv * 1024]); GLD16(bB1, &Bs[0][wv * 1024 + 512]);
    __syncthreads();                      // step-0 tile visible

    #pragma unroll
    for (int st = 0; st < 24; ++st) {
      const int cur = st & 1;
      const int nxt = cur ^ 1;

      if (st + 1 < 24) {                  // issue next stage FIRST (latency
        const int sn = st + 1;            // flies under ds_read + MFMA)
        const int aO = ((sn >> 3) == 1 ? 256 : 0) + (sn & 7) * 32;  // constexpr
        const int bO = ((sn >> 3) == 2 ? 256 : 0) + (sn & 7) * 32;  // constexpr
        GLD16(aB0 + aO, &As[nxt][wv * 1024]);
        GLD16(aB1 + aO, &As[nxt][wv * 1024 + 512]);
        GLD16(bB0 + bO, &Bs[nxt][wv * 1024]);
        GLD16(bB1 + bO, &Bs[nxt][wv * 1024 + 512]);
      }

      f16x8 af[4], bf[4];
      #pragma unroll
      for (int f = 0; f < 4; ++f) {
        af[f] = *(const f16x8*)(&As[cur][(wr * 64 + f * 16 + lc) * 32 + ks]);
        bf[f] = *(const f16x8*)(&Bs[cur][(wc * 64 + f * 16 + lc) * 32 + ks]);
      }

      #pragma unroll
      for (int fm = 0; fm < 4; ++fm)
        #pragma unroll
        for (int fn = 0; fn < 4; ++fn)
          acc[fm][fn] = __builtin_amdgcn_mfma_f32_16x16x32_f16(
              af[fm], bf[fn], acc[fm][fn], 0, 0, 0);

      __syncthreads();                    // ONE barrier/step: drains vmcnt
                                          // (stage st+1 done) + lgkm (reads
                                          // of buf[cur] done by all waves)
    }

    // fold this col-tile: 2-deep insert, cols strictly ascending over ct,fn
    float e2v[4];
    #pragma unroll
    for (int fn = 0; fn < 4; ++fn)
      e2v[fn] = e2[colbase + ct * 128 + wc * 64 + fn * 16 + lc];

    #pragma unroll
    for (int fm = 0; fm < 4; ++fm) {
      #pragma unroll
      for (int j = 0; j < 4; ++j) {
        const int s = fm * 4 + j;
        #pragma unroll
        for (int fn = 0; fn < 4; ++fn) {
          const int col = colbase + ct * 128 + wc * 64 + fn * 16 + lc;
          const float t = fmaf(nts, acc[fm][fn][j], e2v[fn]);
          if (t < t1[s]) {
            t2[s] = t1[s]; i2[s] = i1[s]; t1[s] = t; i1[s] = col;
          } else if (t < t2[s]) {
            t2[s] = t; i2[s] = col;
          }
        }
      }
    }
  }

  // 16-lane butterfly 2-deep merge within each kc row-group (lexicographic)
  #pragma unroll
  for (int s = 0; s < 16; ++s) {
    #pragma unroll
    for (int m = 1; m < 16; m <<= 1) {
      const float p1 = __shfl_xor(t1[s], m);
      const float p2 = __shfl_xor(t2[s], m);
      const int   q1 = __shfl_xor(i1[s], m);
      const int   q2 = __shfl_xor(i2[s], m);
      const bool pl = (p1 < t1[s]) || (p1 == t1[s] && q1 < i1[s]);
      float n1, n2; int m1, m2;
      if (pl) {
        n1 = p1; m1 = q1;
        const bool sl = (t1[s] < p2) || (t1[s] == p2 && i1[s] < q2);
        n2 = sl ? t1[s] : p2; m2 = sl ? i1[s] : q2;
      } else {
        n1 = t1[s]; m1 = i1[s];
        const bool sl = (p1 < t2[s]) || (p1 == t2[s] && q1 < i2[s]);
        n2 = sl ? p1 : t2[s]; m2 = sl ? q1 : i2[s];
      }
      t1[s] = n1; i1[s] = m1; t2[s] = n2; i2[s] = m2;
    }
  }

  // each wave-half writes its top-2 per owned row: cand[row][cg][wc*2+{0,1}]
  if (lc == 0) {
    #pragma unroll
    for (int fm = 0; fm < 4; ++fm)
      #pragma unroll
      for (int j = 0; j < 4; ++j) {
        const int s    = fm * 4 + j;
        const int rloc = wr * 64 + fm * 16 + kc * 4 + j;
        const size_t base = ((size_t)(row0 + rloc) * 8 + cg) * 4 + wc * 2;
        cand[base]     = i1[s];
        cand[base + 1] = i2[s];
      }
  }
}

// ---------------------------------------------------------------------------
// exact recheck: for each row, recompute numpy-exact f32 distance for the 32
// candidates and take lexicographic (s, k) min — identical arithmetic to the
// previously-passing VALU kernel (serial ascending-d fmaf chain, then
// s = fl(fl(x2 - fl(2*acc)) + e2[k])), numpy first-index tie semantics.
__global__ void recheck(const float* __restrict__ X, const float* __restrict__ x2g,
                        const float* __restrict__ Eref, const float* __restrict__ e2ref,
                        const int* __restrict__ cand, int* __restrict__ idxo)
{
  __shared__ float Xl[8][256];
  const int tid  = threadIdx.x;
  const int rg   = tid >> 5;            // row within block (8 rows/block)
  const int lr   = tid & 31;            // candidate lane
  const int row0 = blockIdx.x * 8;
  const int row  = row0 + rg;

  {
    const float* xp = X + (size_t)row * 256 + lr * 8;
    *(vf4*)(&Xl[rg][lr * 8])     = *(const vf4*)xp;
    *(vf4*)(&Xl[rg][lr * 8 + 4]) = *(const vf4*)(xp + 4);
  }
  __syncthreads();

  int k = cand[(size_t)row * 32 + lr];

  float acc = 0.0f;
  const float* ep = Eref + (size_t)k * 256;
  for (int d4 = 0; d4 < 64; ++d4) {
    const vf4 xv = *(const vf4*)(&Xl[rg][d4 * 4]);
    const vf4 ev = *(const vf4*)(ep + d4 * 4);
    acc = fmaf(xv[0], ev[0], acc);
    acc = fmaf(xv[1], ev[1], acc);
    acc = fmaf(xv[2], ev[2], acc);
    acc = fmaf(xv[3], ev[3], acc);
  }
  float s = __fadd_rn(__fsub_rn(x2g[row], __fmul_rn(2.0f, acc)), e2ref[k]);

  #pragma unroll
  for (int m = 1; m < 32; m <<= 1) {
    const float os = __shfl_xor(s, m);
    const int   ok = __shfl_xor(k, m);
    if (os < s || (os == s && ok < k)) { s = os; k = ok; }
  }
  if (lr == 0) idxo[row] = k;
}

// ----------------------- counts + dw atomics + loss (no OQ/OI writes) ------
__global__ void stats_cd(const float* __restrict__ X, const float* __restrict__ E,
                         const int* __restrict__ idx, float* __restrict__ counts,
                         float* __restrict__ dw, double* __restrict__ loss_acc)
{
  __shared__ double part[4];
  const int tid  = threadIdx.x;
  const int lane = tid & 63, w = tid >> 6;
  const int row  = blockIdx.x * 4 + w;
  const int k    = idx[row];
  const vf4 xv = ((const vf4*)X)[(size_t)row * 64 + lane];
  const vf4 qv = ((const vf4*)E)[(size_t)k * 64 + lane];
  const float d0 = xv[0]-qv[0], d1 = xv[1]-qv[1], d2 = xv[2]-qv[2], d3 = xv[3]-qv[3];
  double ps = (double)(d0*d0 + d1*d1 + d2*d2 + d3*d3);
  #pragma unroll
  for (int o = 32; o; o >>= 1) ps += __shfl_down(ps, o);
  #pragma unroll
  for (int j = 0; j < 4; ++j)
    atomicAdd(dw + (size_t)k * Dim + lane * 4 + j, xv[j]);
  if (lane == 0) {
    part[w] = ps;
    atomicAdd(counts + k, 1.0f);
  }
  __syncthreads();
  if (tid == 0) atomicAdd(loss_acc, part[0] + part[1] + part[2] + part[3]);
}

// quantized gather + index write, LAST (frees OQ region for Xs during argmins)
__global__ void gather_q(const float* __restrict__ E, const int* __restrict__ idx,
                         float* __restrict__ out)
{
  const int tid  = threadIdx.x;
  const int lane = tid & 63, w = tid >> 6;
  const int row  = blockIdx.x * 4 + w;
  const int k    = idx[row];
  ((vf4*)out)[(size_t)row * 64 + lane] = ((const vf4*)E)[(size_t)k * 64 + lane];
  if (lane == 0) out[OI + row] = (float)k;
}

// ------------------------------------------------- per-code EMA scalar updates
__global__ void cs_usage(const float* __restrict__ ecs, const float* __restrict__ usage,
                         const float* __restrict__ counts, float* __restrict__ out,
                         int* __restrict__ pos_cnt)
{
  __shared__ int si[256];
  const int tid = threadIdx.x;
  const int k   = blockIdx.x * 256 + tid;
  const float cnt = counts[k];
  const float ncs = __fadd_rn(__fmul_rn(ecs[k], 0.99f), __fmul_rn(0.01f, cnt));
  out[OCS + k] = ncs;
  const float nus = __fadd_rn(__fmul_rn(usage[k], 0.99f), __fmul_rn(0.01f, cnt));
  out[OU + k] = nus;
  si[tid] = (nus > 0.0f) ? 1 : 0;
  __syncthreads();
  for (int s = 128; s; s >>= 1) {
    if (tid < s) si[tid] += si[tid + s];
    __syncthreads();
  }
  if (tid == 0) atomicAdd(pos_cnt, si[0]);
}

// n = np.sum(new_cs), numpy pairwise over 4096
__global__ void n_np_kernel(const float* __restrict__ ncs, float* __restrict__ nf) {
  __shared__ float leaf[32];
  const int t = threadIdx.x;
  if (t < 32) {
    const float* a = ncs + t * 128;
    float r[8];
    #pragma unroll
    for (int j = 0; j < 8; ++j) r[j] = a[j];
    for (int i = 8; i < 128; i += 8)
      #pragma unroll
      for (int j = 0; j < 8; ++j) r[j] = __fadd_rn(r[j], a[i + j]);
    leaf[t] = __fadd_rn(__fadd_rn(__fadd_rn(r[0], r[1]), __fadd_rn(r[2], r[3])),
                        __fadd_rn(__fadd_rn(r[4], r[5]), __fadd_rn(r[6], r[7])));
  }
  __syncthreads();
  if (t == 0) {
    float v[32];
    #pragma unroll
    for (int i = 0; i < 32; ++i) v[i] = leaf[i];
    for (int n = 32; n > 1; n >>= 1)
      for (int i = 0; i < (n >> 1); ++i) v[i] = __fadd_rn(v[2 * i], v[2 * i + 1]);
    *nf = v[0];
  }
}

// new_ema_w (in place over dw accum) and pre-embedding (written to out[OE];
// all consumers of the pre-reset embedding run before finalize_k), numpy order
__global__ void emb_pre(const float* __restrict__ emaw, float* __restrict__ out,
                        const float* __restrict__ nf)
{
  const int k = blockIdx.x;
  const int d = threadIdx.x;
  const size_t o = (size_t)k * Dim + d;
  const float dwv = out[OW + o];
  const float w = __fadd_rn(__fmul_rn(emaw[o], 0.99f), __fmul_rn(0.01f, dwv));
  out[OW + o] = w;
  const float nv  = *nf;
  const float ncs = out[OCS + k];
  const float cs  = __fmul_rn(__fdiv_rn(__fadd_rn(ncs, EPSf), __fadd_rn(nv, KEPSf)), nv);
  out[OE + o] = __fdiv_rn(w, cs);
}

__global__ void used_scatter(const int* __restrict__ idx2, int* __restrict__ used) {
  const int i = blockIdx.x * 256 + threadIdx.x;
  used[idx2[i]] = 1;
}

__global__ void finalize_k(const float* __restrict__ X, const int* __restrict__ used,
                           const int* __restrict__ steps_in, const int* __restrict__ rnd,
                           float* __restrict__ out)
{
  const int k = blockIdx.x, d = threadIdx.x;
  const int u = used[k];
  const float st = u ? 0.0f : (float)steps_in[k] + 1.0f;
  const bool dead = st > 100.0f;
  if (dead) out[OE + (size_t)k * Dim + d] = X[(size_t)rnd[k] * Dim + d];
  if (d == 0) out[OS + k] = dead ? 0.0f : st;
}

__global__ void write_scalars(const double* __restrict__ loss_acc,
                              const int* __restrict__ pos_cnt, float* __restrict__ out)
{
  if (threadIdx.x == 0) {
    out[OL] = 0.25f * (float)(*loss_acc / (double)((size_t)Ncnt * Dim));
    out[OR] = (float)(*pos_cnt) / (float)Kcb;
  }
}

// ---------------------------------------------------------------------- launch
extern "C" void kernel_launch(void* const* d_in, const int* in_sizes, int n_in,
                              void* d_out, int out_size, void* d_ws, size_t ws_size,
                              hipStream_t stream)
{
  const float* X     = (const float*)d_in[0];
  const float* E     = (const float*)d_in[1];
  const float* ECS   = (const float*)d_in[2];
  const float* EMAW  = (const float*)d_in[3];
  const float* USAGE = (const float*)d_in[4];
  const int*   STEPS = (const int*)d_in[5];
  const int*   RND   = (const int*)d_in[6];
  float* out = (float*)d_out;

  float* wsf = (float*)d_ws;
  float*  counts   = wsf;                          // [4096]  zeroed
  int*    used     = (int*)(wsf + 4096);           // [4096]  zeroed
  double* loss_acc = (double*)(wsf + 8192);        //         zeroed
  float*  nf       = wsf + 8194;
  int*    pos_cnt  = (int*)(wsf + 8195);
  const size_t ZN  = 8200;                         // zero region, floats
  float* x2g  = wsf + 8320;                        // [32768]          -> 41088
  float* e2   = wsf + 41088;                       // [4096]           -> 45184
  float* e2p  = wsf + 45184;                       // [4096]           -> 49280
  int*   idx1 = (int*)(wsf + 49280);               // [32768]          -> 82048
  int*   idx2 = (int*)(wsf + 82048);               // [32768]          -> 114816
  f16*   Es   = (f16*)(wsf + 114816);              // 4096*512 f16 = 1048576 f -> 1163392
  int*   cand = (int*)(wsf + 1163392);             // 32768*32 ints    -> 2211968
  // pre-reset embedding lives directly in out[OE] (consumers run pre-reset).
  // Xs (32768x512 f16 = 32 MiB) parks exactly in the OQ output region;
  // gather_q rewrites OQ after the second argmin is done.
  f16*   Xsp  = (f16*)out;

  hipMemsetAsync(d_ws, 0, ZN * sizeof(float), stream);
  hipMemsetAsync(out + OW, 0, (size_t)Kcb * Dim * sizeof(float), stream); // dw accum

  rowsq_np     <<<Ncnt / 256, 256, 0, stream>>>(X, x2g, Ncnt);
  rowsq_np     <<<Kcb / 256,  256, 0, stream>>>(E, e2, Kcb);
  split_rows   <<<Ncnt / 4,   256, 0, stream>>>(X, Xsp, 64.0f, Ncnt);      // 2^6
  split_rows   <<<Kcb / 4,    256, 0, stream>>>(E, Es, 16777216.0f, Kcb);  // 2^24
  mfma_argmin  <<<2048,       256, 0, stream>>>(Xsp, Es, e2, 0x1p-29f, cand);
  recheck      <<<Ncnt / 8,   256, 0, stream>>>(X, x2g, E, e2, cand, idx1);
  stats_cd     <<<Ncnt / 4,   256, 0, stream>>>(X, E, idx1, counts, out + OW, loss_acc);
  cs_usage     <<<Kcb / 256,  256, 0, stream>>>(ECS, USAGE, counts, out, pos_cnt);
  n_np_kernel  <<<1,          64,  0, stream>>>(out + OCS, nf);
  emb_pre      <<<Kcb,        256, 0, stream>>>(EMAW, out, nf);
  rowsq_np     <<<Kcb / 256,  256, 0, stream>>>(out + OE, e2p, Kcb);
  split_rows   <<<Kcb / 4,    256, 0, stream>>>(out + OE, Es, 256.0f, Kcb); // 2^8
  mfma_argmin  <<<2048,       256, 0, stream>>>(Xsp, Es, e2p, 0x1p-13f, cand);
  recheck      <<<Ncnt / 8,   256, 0, stream>>>(X, x2g, out + OE, e2p, cand, idx2);
  used_scatter <<<Ncnt / 256, 256, 0, stream>>>(idx2, used);
  finalize_k   <<<Kcb,        256, 0, stream>>>(X, used, STEPS, RND, out);
  gather_q     <<<Ncnt / 4,   256, 0, stream>>>(E, idx1, out);
  write_scalars<<<1,          64,  0, stream>>>(loss_acc, pos_cnt, out);

  (void)in_sizes; (void)n_in; (void)out_size; (void)ws_size;
}

// Round 8
// 1857.907 us; speedup vs baseline: 3.9451x; 1.0553x over previous
//
#include <hip/hip_runtime.h>
#include <math.h>

typedef float vf4 __attribute__((ext_vector_type(4)));
typedef _Float16 f16;
typedef _Float16 f16x8 __attribute__((ext_vector_type(8)));
typedef _Float16 f16x4 __attribute__((ext_vector_type(4)));
typedef float f32x4 __attribute__((ext_vector_type(4)));

static constexpr int Ncnt = 32768;
static constexpr int Kcb  = 4096;
static constexpr int Dim  = 256;

static constexpr float EPSf  = 1e-5f;
static constexpr float KEPSf = (float)(4096.0 * 1e-5);

// d_out float offsets (reference return order, flattened)
static constexpr size_t OQ  = 0;
static constexpr size_t OI  = (size_t)Ncnt * Dim;
static constexpr size_t OL  = OI + Ncnt;
static constexpr size_t OE  = OL + 1;
static constexpr size_t OCS = OE + (size_t)Kcb * Dim;
static constexpr size_t OW  = OCS + Kcb;
static constexpr size_t OU  = OW + (size_t)Kcb * Dim;
static constexpr size_t OS  = OU + Kcb;
static constexpr size_t OR  = OS + Kcb;

// async global->LDS, 16B per lane; LDS dest is wave-uniform base + lane*16
#define GLD16(gp, lp)                                                   \
  __builtin_amdgcn_global_load_lds(                                     \
      (const __attribute__((address_space(1))) void*)(gp),              \
      (__attribute__((address_space(3))) void*)(lp), 16, 0, 0)

// ---------------------------------------------------------------------------
// numpy pairwise_sum over fl(p[i]*p[i]) for n=256 (bit-exact np.sum(x*x,1))
__device__ __forceinline__ float np_sq256(const float* __restrict__ p) {
  float tot[2];
  #pragma unroll
  for (int h = 0; h < 2; ++h) {
    const float* a = p + h * 128;
    float r[8];
    #pragma unroll
    for (int j = 0; j < 8; ++j) r[j] = __fmul_rn(a[j], a[j]);
    for (int i = 8; i < 128; i += 8)
      #pragma unroll
      for (int j = 0; j < 8; ++j) r[j] = __fadd_rn(r[j], __fmul_rn(a[i + j], a[i + j]));
    tot[h] = __fadd_rn(__fadd_rn(__fadd_rn(r[0], r[1]), __fadd_rn(r[2], r[3])),
                       __fadd_rn(__fadd_rn(r[4], r[5]), __fadd_rn(r[6], r[7])));
  }
  return __fadd_rn(tot[0], tot[1]);
}

__global__ void rowsq_np(const float* __restrict__ E, float* __restrict__ e2, int rows) {
  const int k = blockIdx.x * 256 + threadIdx.x;
  if (k < rows) e2[k] = np_sq256(E + (size_t)k * Dim);
}

// ---------------------------------------------------------------------------
// 2-limb f16 split with exact power-of-2 scaling:
//   t = v*scale (exact); hi = f16(t); lo = f16(t - hi)  (t - (f32)hi exact)
// layout: dst row = [hi(256) | lo(256)]
__global__ void split_rows(const float* __restrict__ src, f16* __restrict__ dst,
                           const float scale, const int rows)
{
  const int i   = blockIdx.x * 256 + threadIdx.x;
  const int row = i >> 6;
  const int d0  = (i & 63) * 4;
  if (row >= rows) return;
  const vf4 v = *(const vf4*)(src + (size_t)row * 256 + d0);
  f16x4 hi, lo;
  #pragma unroll
  for (int j = 0; j < 4; ++j) {
    const float t = __fmul_rn(v[j], scale);
    const f16 h   = (f16)t;
    const float r = __fsub_rn(t, (float)h);
    hi[j] = h;
    lo[j] = (f16)r;
  }
  *(f16x4*)(dst + (size_t)row * 512 + d0)       = hi;
  *(f16x4*)(dst + (size_t)row * 512 + 256 + d0) = lo;
}

// ---------------------------------------------------------------------------
// MFMA candidate pass. Grid: 2048 = 256 row-groups x 8 col-groups. Block =
// 128 rows x 512 cols (4 col-tiles of 128). Tile 128x128, 4 waves (2x2 of
// 64x64), BK=32. Virtual K = 768 as 3 segments of 8 steps:
//   seg0: A off 0   B off 0    (hiX*hiE)
//   seg1: A off 256 B off 0    (loX*hiE)
//   seg2: A off 0   B off 256  (hiX*loE)
// Staging: global_load_lds width=16 into TRIPLE-BUFFERED LDS with COUNTED
// vmcnt (T3+T4): stage(g+2) issued at step g, so 4 loads stay in flight
// across the barrier; gate = inline-asm s_waitcnt vmcnt(4) + raw s_barrier
// + sched_barrier(0) (NOT __syncthreads, which drains vmcnt to 0 and was
// the measured ~2180 cyc/step latency exposure in rounds 3/4/6).
// Buffer index = st % 3 (24 % 3 == 0 -> consistent across ct); buffer
// (g+2)%3 was last read at step g-1, whose reads complete before the step-g
// barrier (MFMA consumption forces lgkm drain) -> write-after-read safe.
// st==23 uses vmcnt(0) (final-step correctness; costs 4 early drains / 96).
// launch_bounds(256,2): cap 256 on the UNIFIED VGPR+AGPR file. (256,4)
// = cap 128 -> acc spill to scratch, 6 GB/dispatch writes, 5x regression
// (round-5 lesson).
// LDS dest is linear (lane l -> base+l*16); global source chunk pre-swizzled
//   chunk = (l&3) ^ ((l>>3)&3)  ==  slot ^ ((row>>1)&3)
// so frag reads use slot ks = (kc ^ ((lc>>1)&3))*8 (proven involution).
// Proxy t = fmaf(-two_scale, acc, e2[col]) (x2 row-constant: rank-equal).
// Per-thread-slot 2-deep (t,idx); 16-lane butterfly 2-deep merge; each
// wave-half (wc) writes its top-2 -> cand[row][cg][4]. Exact argmin is
// recomputed over candidates by recheck() with numpy-exact f32 semantics.
#define AOF(s) ((((s) >> 3) == 1 ? 256 : 0) + ((s) & 7) * 32)
#define BOF(s) ((((s) >> 3) == 2 ? 256 : 0) + ((s) & 7) * 32)
#define STAGE4(aP0, aP1, bP0, bP1, bufi)                                \
  do {                                                                  \
    GLD16((aP0), &As[(bufi)][wv * 1024]);                               \
    GLD16((aP1), &As[(bufi)][wv * 1024 + 512]);                         \
    GLD16((bP0), &Bs[(bufi)][wv * 1024]);                               \
    GLD16((bP1), &Bs[(bufi)][wv * 1024 + 512]);                         \
  } while (0)

__global__ __launch_bounds__(256, 2) void mfma_argmin(
    const f16* __restrict__ Xs, const f16* __restrict__ Es,
    const float* __restrict__ e2, const float two_scale,
    int* __restrict__ cand)
{
  __shared__ __align__(16) f16 As[3][128 * 32];
  __shared__ __align__(16) f16 Bs[3][128 * 32];

  const int tid  = threadIdx.x;
  const int bid  = blockIdx.x;
  const int row0 = (bid >> 3) * 128;
  const int cg   = bid & 7;
  const int colbase = cg * 512;

  const int l  = tid & 63;
  const int wv = tid >> 6;
  const int wr = wv >> 1;
  const int wc = wv & 1;
  const int lc = l & 15;
  const int kc = l >> 4;

  // staging: wave wv stages rows [wv*32, wv*32+16) (issue0) and +16 (issue1)
  const int srow = wv * 32 + (l >> 2);
  const int chs  = (l & 3) ^ ((l >> 3) & 3);

  const f16* aB0 = Xs + (size_t)(row0 + srow) * 512 + chs * 8;
  const f16* aB1 = aB0 + 16 * 512;
  const f16* bBase0 = Es + (size_t)(colbase + srow) * 512 + chs * 8;
  const f16* bBase1 = bBase0 + 16 * 512;

  // frag-read swizzled k-slot (row = ..+lc; (row>>1)&3 == (lc>>1)&3)
  const int ks = (kc ^ ((lc >> 1) & 3)) * 8;

  const float nts = -two_scale;

  float t1[16], t2[16];
  int   i1[16], i2[16];
  #pragma unroll
  for (int s = 0; s < 16; ++s) {
    t1[s] = INFINITY; t2[s] = INFINITY; i1[s] = 0x7fffffff; i2[s] = 0x7fffffff;
  }

  // prologue: stages 0 and 1 of ct=0 (8 loads in flight)
  STAGE4(aB0 + AOF(0), aB1 + AOF(0), bBase0 + BOF(0), bBase1 + BOF(0), 0);
  STAGE4(aB0 + AOF(1), aB1 + AOF(1), bBase0 + BOF(1), bBase1 + BOF(1), 1);

  #pragma unroll 1
  for (int ct = 0; ct < 4; ++ct) {
    const f16* bC0 = bBase0 + ct * 65536;   // + ct * 128 rows * 512 f16
    const f16* bC1 = bBase1 + ct * 65536;

    f32x4 acc[4][4];
    #pragma unroll
    for (int i = 0; i < 4; ++i)
      #pragma unroll
      for (int j = 0; j < 4; ++j)
        acc[i][j] = (f32x4){0.0f, 0.0f, 0.0f, 0.0f};

    #pragma unroll
    for (int st = 0; st < 24; ++st) {
      // gate: this step's stage complete everywhere; 4 newer loads stay
      // in flight (never drain to 0 in steady state — T4)
      if (st == 23) { asm volatile("s_waitcnt vmcnt(0)" ::: "memory"); }
      else          { asm volatile("s_waitcnt vmcnt(4)" ::: "memory"); }
      __builtin_amdgcn_s_barrier();
      __builtin_amdgcn_sched_barrier(0);

      const int cur = st % 3;
      f16x8 af[4], bf[4];
      #pragma unroll
      for (int f = 0; f < 4; ++f) {
        af[f] = *(const f16x8*)(&As[cur][(wr * 64 + f * 16 + lc) * 32 + ks]);
        bf[f] = *(const f16x8*)(&Bs[cur][(wc * 64 + f * 16 + lc) * 32 + ks]);
      }

      // issue stage(g+2) into buf (st+2)%3 (last read at step g-1: WAR-safe)
      if (st + 2 < 24) {
        STAGE4(aB0 + AOF(st + 2), aB1 + AOF(st + 2),
               bC0 + BOF(st + 2), bC1 + BOF(st + 2), (st + 2) % 3);
      } else if (ct < 3) {                  // seam: next ct's stage st-22
        STAGE4(aB0 + AOF(st - 22), aB1 + AOF(st - 22),
               bC0 + 65536 + BOF(st - 22), bC1 + 65536 + BOF(st - 22),
               (st + 2) % 3);
      }

      __builtin_amdgcn_s_setprio(1);
      #pragma unroll
      for (int fm = 0; fm < 4; ++fm)
        #pragma unroll
        for (int fn = 0; fn < 4; ++fn)
          acc[fm][fn] = __builtin_amdgcn_mfma_f32_16x16x32_f16(
              af[fm], bf[fn], acc[fm][fn], 0, 0, 0);
      __builtin_amdgcn_s_setprio(0);
    }

    // fold this col-tile: 2-deep insert, cols strictly ascending over ct,fn
    float e2v[4];
    #pragma unroll
    for (int fn = 0; fn < 4; ++fn)
      e2v[fn] = e2[colbase + ct * 128 + wc * 64 + fn * 16 + lc];

    #pragma unroll
    for (int fm = 0; fm < 4; ++fm) {
      #pragma unroll
      for (int j = 0; j < 4; ++j) {
        const int s = fm * 4 + j;
        #pragma unroll
        for (int fn = 0; fn < 4; ++fn) {
          const int col = colbase + ct * 128 + wc * 64 + fn * 16 + lc;
          const float t = fmaf(nts, acc[fm][fn][j], e2v[fn]);
          if (t < t1[s]) {
            t2[s] = t1[s]; i2[s] = i1[s]; t1[s] = t; i1[s] = col;
          } else if (t < t2[s]) {
            t2[s] = t; i2[s] = col;
          }
        }
      }
    }
  }

  // 16-lane butterfly 2-deep merge within each kc row-group (lexicographic)
  #pragma unroll
  for (int s = 0; s < 16; ++s) {
    #pragma unroll
    for (int m = 1; m < 16; m <<= 1) {
      const float p1 = __shfl_xor(t1[s], m);
      const float p2 = __shfl_xor(t2[s], m);
      const int   q1 = __shfl_xor(i1[s], m);
      const int   q2 = __shfl_xor(i2[s], m);
      const bool pl = (p1 < t1[s]) || (p1 == t1[s] && q1 < i1[s]);
      float n1, n2; int m1, m2;
      if (pl) {
        n1 = p1; m1 = q1;
        const bool sl = (t1[s] < p2) || (t1[s] == p2 && i1[s] < q2);
        n2 = sl ? t1[s] : p2; m2 = sl ? i1[s] : q2;
      } else {
        n1 = t1[s]; m1 = i1[s];
        const bool sl = (p1 < t2[s]) || (p1 == t2[s] && q1 < i2[s]);
        n2 = sl ? p1 : t2[s]; m2 = sl ? q1 : i2[s];
      }
      t1[s] = n1; i1[s] = m1; t2[s] = n2; i2[s] = m2;
    }
  }

  // each wave-half writes its top-2 per owned row: cand[row][cg][wc*2+{0,1}]
  if (lc == 0) {
    #pragma unroll
    for (int fm = 0; fm < 4; ++fm)
      #pragma unroll
      for (int j = 0; j < 4; ++j) {
        const int s    = fm * 4 + j;
        const int rloc = wr * 64 + fm * 16 + kc * 4 + j;
        const size_t base = ((size_t)(row0 + rloc) * 8 + cg) * 4 + wc * 2;
        cand[base]     = i1[s];
        cand[base + 1] = i2[s];
      }
  }
}

// ---------------------------------------------------------------------------
// exact recheck: for each row, recompute numpy-exact f32 distance for the 32
// candidates and take lexicographic (s, k) min — identical arithmetic to the
// previously-passing VALU kernel (serial ascending-d fmaf chain, then
// s = fl(fl(x2 - fl(2*acc)) + e2[k])), numpy first-index tie semantics.
__global__ void recheck(const float* __restrict__ X, const float* __restrict__ x2g,
                        const float* __restrict__ Eref, const float* __restrict__ e2ref,
                        const int* __restrict__ cand, int* __restrict__ idxo)
{
  __shared__ float Xl[8][256];
  const int tid  = threadIdx.x;
  const int rg   = tid >> 5;            // row within block (8 rows/block)
  const int lr   = tid & 31;            // candidate lane
  const int row0 = blockIdx.x * 8;
  const int row  = row0 + rg;

  {
    const float* xp = X + (size_t)row * 256 + lr * 8;
    *(vf4*)(&Xl[rg][lr * 8])     = *(const vf4*)xp;
    *(vf4*)(&Xl[rg][lr * 8 + 4]) = *(const vf4*)(xp + 4);
  }
  __syncthreads();

  int k = cand[(size_t)row * 32 + lr];

  float acc = 0.0f;
  const float* ep = Eref + (size_t)k * 256;
  for (int d4 = 0; d4 < 64; ++d4) {
    const vf4 xv = *(const vf4*)(&Xl[rg][d4 * 4]);
    const vf4 ev = *(const vf4*)(ep + d4 * 4);
    acc = fmaf(xv[0], ev[0], acc);
    acc = fmaf(xv[1], ev[1], acc);
    acc = fmaf(xv[2], ev[2], acc);
    acc = fmaf(xv[3], ev[3], acc);
  }
  float s = __fadd_rn(__fsub_rn(x2g[row], __fmul_rn(2.0f, acc)), e2ref[k]);

  #pragma unroll
  for (int m = 1; m < 32; m <<= 1) {
    const float os = __shfl_xor(s, m);
    const int   ok = __shfl_xor(k, m);
    if (os < s || (os == s && ok < k)) { s = os; k = ok; }
  }
  if (lr == 0) idxo[row] = k;
}

// ----------------------- counts + dw atomics + loss (no OQ/OI writes) ------
__global__ void stats_cd(const float* __restrict__ X, const float* __restrict__ E,
                         const int* __restrict__ idx, float* __restrict__ counts,
                         float* __restrict__ dw, double* __restrict__ loss_acc)
{
  __shared__ double part[4];
  const int tid  = threadIdx.x;
  const int lane = tid & 63, w = tid >> 6;
  const int row  = blockIdx.x * 4 + w;
  const int k    = idx[row];
  const vf4 xv = ((const vf4*)X)[(size_t)row * 64 + lane];
  const vf4 qv = ((const vf4*)E)[(size_t)k * 64 + lane];
  const float d0 = xv[0]-qv[0], d1 = xv[1]-qv[1], d2 = xv[2]-qv[2], d3 = xv[3]-qv[3];
  double ps = (double)(d0*d0 + d1*d1 + d2*d2 + d3*d3);
  #pragma unroll
  for (int o = 32; o; o >>= 1) ps += __shfl_down(ps, o);
  #pragma unroll
  for (int j = 0; j < 4; ++j)
    atomicAdd(dw + (size_t)k * Dim + lane * 4 + j, xv[j]);
  if (lane == 0) {
    part[w] = ps;
    atomicAdd(counts + k, 1.0f);
  }
  __syncthreads();
  if (tid == 0) atomicAdd(loss_acc, part[0] + part[1] + part[2] + part[3]);
}

// quantized gather + index write, LAST (frees OQ region for Xs during argmins)
__global__ void gather_q(const float* __restrict__ E, const int* __restrict__ idx,
                         float* __restrict__ out)
{
  const int tid  = threadIdx.x;
  const int lane = tid & 63, w = tid >> 6;
  const int row  = blockIdx.x * 4 + w;
  const int k    = idx[row];
  ((vf4*)out)[(size_t)row * 64 + lane] = ((const vf4*)E)[(size_t)k * 64 + lane];
  if (lane == 0) out[OI + row] = (float)k;
}

// ------------------------------------------------- per-code EMA scalar updates
__global__ void cs_usage(const float* __restrict__ ecs, const float* __restrict__ usage,
                         const float* __restrict__ counts, float* __restrict__ out,
                         int* __restrict__ pos_cnt)
{
  __shared__ int si[256];
  const int tid = threadIdx.x;
  const int k   = blockIdx.x * 256 + tid;
  const float cnt = counts[k];
  const float ncs = __fadd_rn(__fmul_rn(ecs[k], 0.99f), __fmul_rn(0.01f, cnt));
  out[OCS + k] = ncs;
  const float nus = __fadd_rn(__fmul_rn(usage[k], 0.99f), __fmul_rn(0.01f, cnt));
  out[OU + k] = nus;
  si[tid] = (nus > 0.0f) ? 1 : 0;
  __syncthreads();
  for (int s = 128; s; s >>= 1) {
    if (tid < s) si[tid] += si[tid + s];
    __syncthreads();
  }
  if (tid == 0) atomicAdd(pos_cnt, si[0]);
}

// n = np.sum(new_cs), numpy pairwise over 4096
__global__ void n_np_kernel(const float* __restrict__ ncs, float* __restrict__ nf) {
  __shared__ float leaf[32];
  const int t = threadIdx.x;
  if (t < 32) {
    const float* a = ncs + t * 128;
    float r[8];
    #pragma unroll
    for (int j = 0; j < 8; ++j) r[j] = a[j];
    for (int i = 8; i < 128; i += 8)
      #pragma unroll
      for (int j = 0; j < 8; ++j) r[j] = __fadd_rn(r[j], a[i + j]);
    leaf[t] = __fadd_rn(__fadd_rn(__fadd_rn(r[0], r[1]), __fadd_rn(r[2], r[3])),
                        __fadd_rn(__fadd_rn(r[4], r[5]), __fadd_rn(r[6], r[7])));
  }
  __syncthreads();
  if (t == 0) {
    float v[32];
    #pragma unroll
    for (int i = 0; i < 32; ++i) v[i] = leaf[i];
    for (int n = 32; n > 1; n >>= 1)
      for (int i = 0; i < (n >> 1); ++i) v[i] = __fadd_rn(v[2 * i], v[2 * i + 1]);
    *nf = v[0];
  }
}

// new_ema_w (in place over dw accum) and pre-embedding (written to out[OE];
// all consumers of the pre-reset embedding run before finalize_k), numpy order
__global__ void emb_pre(const float* __restrict__ emaw, float* __restrict__ out,
                        const float* __restrict__ nf)
{
  const int k = blockIdx.x;
  const int d = threadIdx.x;
  const size_t o = (size_t)k * Dim + d;
  const float dwv = out[OW + o];
  const float w = __fadd_rn(__fmul_rn(emaw[o], 0.99f), __fmul_rn(0.01f, dwv));
  out[OW + o] = w;
  const float nv  = *nf;
  const float ncs = out[OCS + k];
  const float cs  = __fmul_rn(__fdiv_rn(__fadd_rn(ncs, EPSf), __fadd_rn(nv, KEPSf)), nv);
  out[OE + o] = __fdiv_rn(w, cs);
}

__global__ void used_scatter(const int* __restrict__ idx2, int* __restrict__ used) {
  const int i = blockIdx.x * 256 + threadIdx.x;
  used[idx2[i]] = 1;
}

__global__ void finalize_k(const float* __restrict__ X, const int* __restrict__ used,
                           const int* __restrict__ steps_in, const int* __restrict__ rnd,
                           float* __restrict__ out)
{
  const int k = blockIdx.x, d = threadIdx.x;
  const int u = used[k];
  const float st = u ? 0.0f : (float)steps_in[k] + 1.0f;
  const bool dead = st > 100.0f;
  if (dead) out[OE + (size_t)k * Dim + d] = X[(size_t)rnd[k] * Dim + d];
  if (d == 0) out[OS + k] = dead ? 0.0f : st;
}

__global__ void write_scalars(const double* __restrict__ loss_acc,
                              const int* __restrict__ pos_cnt, float* __restrict__ out)
{
  if (threadIdx.x == 0) {
    out[OL] = 0.25f * (float)(*loss_acc / (double)((size_t)Ncnt * Dim));
    out[OR] = (float)(*pos_cnt) / (float)Kcb;
  }
}

// ---------------------------------------------------------------------- launch
extern "C" void kernel_launch(void* const* d_in, const int* in_sizes, int n_in,
                              void* d_out, int out_size, void* d_ws, size_t ws_size,
                              hipStream_t stream)
{
  const float* X     = (const float*)d_in[0];
  const float* E     = (const float*)d_in[1];
  const float* ECS   = (const float*)d_in[2];
  const float* EMAW  = (const float*)d_in[3];
  const float* USAGE = (const float*)d_in[4];
  const int*   STEPS = (const int*)d_in[5];
  const int*   RND   = (const int*)d_in[6];
  float* out = (float*)d_out;

  float* wsf = (float*)d_ws;
  float*  counts   = wsf;                          // [4096]  zeroed
  int*    used     = (int*)(wsf + 4096);           // [4096]  zeroed
  double* loss_acc = (double*)(wsf + 8192);        //         zeroed
  float*  nf       = wsf + 8194;
  int*    pos_cnt  = (int*)(wsf + 8195);
  const size_t ZN  = 8200;                         // zero region, floats
  float* x2g  = wsf + 8320;                        // [32768]          -> 41088
  float* e2   = wsf + 41088;                       // [4096]           -> 45184
  float* e2p  = wsf + 45184;                       // [4096]           -> 49280
  int*   idx1 = (int*)(wsf + 49280);               // [32768]          -> 82048
  int*   idx2 = (int*)(wsf + 82048);               // [32768]          -> 114816
  f16*   Es   = (f16*)(wsf + 114816);              // 4096*512 f16 = 1048576 f -> 1163392
  int*   cand = (int*)(wsf + 1163392);             // 32768*32 ints    -> 2211968
  // pre-reset embedding lives directly in out[OE] (consumers run pre-reset).
  // Xs (32768x512 f16 = 32 MiB) parks exactly in the OQ output region;
  // gather_q rewrites OQ after the second argmin is done.
  f16*   Xsp  = (f16*)out;

  hipMemsetAsync(d_ws, 0, ZN * sizeof(float), stream);
  hipMemsetAsync(out + OW, 0, (size_t)Kcb * Dim * sizeof(float), stream); // dw accum

  rowsq_np     <<<Ncnt / 256, 256, 0, stream>>>(X, x2g, Ncnt);
  rowsq_np     <<<Kcb / 256,  256, 0, stream>>>(E, e2, Kcb);
  split_rows   <<<Ncnt / 4,   256, 0, stream>>>(X, Xsp, 64.0f, Ncnt);      // 2^6
  split_rows   <<<Kcb / 4,    256, 0, stream>>>(E, Es, 16777216.0f, Kcb);  // 2^24
  mfma_argmin  <<<2048,       256, 0, stream>>>(Xsp, Es, e2, 0x1p-29f, cand);
  recheck      <<<Ncnt / 8,   256, 0, stream>>>(X, x2g, E, e2, cand, idx1);
  stats_cd     <<<Ncnt / 4,   256, 0, stream>>>(X, E, idx1, counts, out + OW, loss_acc);
  cs_usage     <<<Kcb / 256,  256, 0, stream>>>(ECS, USAGE, counts, out, pos_cnt);
  n_np_kernel  <<<1,          64,  0, stream>>>(out + OCS, nf);
  emb_pre      <<<Kcb,        256, 0, stream>>>(EMAW, out, nf);
  rowsq_np     <<<Kcb / 256,  256, 0, stream>>>(out + OE, e2p, Kcb);
  split_rows   <<<Kcb / 4,    256, 0, stream>>>(out + OE, Es, 256.0f, Kcb); // 2^8
  mfma_argmin  <<<2048,       256, 0, stream>>>(Xsp, Es, e2p, 0x1p-13f, cand);
  recheck      <<<Ncnt / 8,   256, 0, stream>>>(X, x2g, out + OE, e2p, cand, idx2);
  used_scatter <<<Ncnt / 256, 256, 0, stream>>>(idx2, used);
  finalize_k   <<<Kcb,        256, 0, stream>>>(X, used, STEPS, RND, out);
  gather_q     <<<Ncnt / 4,   256, 0, stream>>>(E, idx1, out);
  write_scalars<<<1,          64,  0, stream>>>(loss_acc, pos_cnt, out);

  (void)in_sizes; (void)n_in; (void)out_size; (void)ws_size;
}

// Round 9
// 1718.941 us; speedup vs baseline: 4.2640x; 1.0808x over previous
//
#include <hip/hip_runtime.h>
#include <math.h>

typedef float vf4 __attribute__((ext_vector_type(4)));
typedef _Float16 f16;
typedef _Float16 f16x8 __attribute__((ext_vector_type(8)));
typedef _Float16 f16x4 __attribute__((ext_vector_type(4)));
typedef float f32x4 __attribute__((ext_vector_type(4)));

static constexpr int Ncnt = 32768;
static constexpr int Kcb  = 4096;
static constexpr int Dim  = 256;

static constexpr float EPSf  = 1e-5f;
static constexpr float KEPSf = (float)(4096.0 * 1e-5);

// d_out float offsets (reference return order, flattened)
static constexpr size_t OQ  = 0;
static constexpr size_t OI  = (size_t)Ncnt * Dim;
static constexpr size_t OL  = OI + Ncnt;
static constexpr size_t OE  = OL + 1;
static constexpr size_t OCS = OE + (size_t)Kcb * Dim;
static constexpr size_t OW  = OCS + Kcb;
static constexpr size_t OU  = OW + (size_t)Kcb * Dim;
static constexpr size_t OS  = OU + Kcb;
static constexpr size_t OR  = OS + Kcb;

// async global->LDS, 16B per lane; LDS dest is wave-uniform base + lane*16
#define GLD16(gp, lp)                                                   \
  __builtin_amdgcn_global_load_lds(                                     \
      (const __attribute__((address_space(1))) void*)(gp),              \
      (__attribute__((address_space(3))) void*)(lp), 16, 0, 0)

// ---------------------------------------------------------------------------
// numpy pairwise_sum over fl(p[i]*p[i]) for n=256 (bit-exact np.sum(x*x,1))
__device__ __forceinline__ float np_sq256(const float* __restrict__ p) {
  float tot[2];
  #pragma unroll
  for (int h = 0; h < 2; ++h) {
    const float* a = p + h * 128;
    float r[8];
    #pragma unroll
    for (int j = 0; j < 8; ++j) r[j] = __fmul_rn(a[j], a[j]);
    for (int i = 8; i < 128; i += 8)
      #pragma unroll
      for (int j = 0; j < 8; ++j) r[j] = __fadd_rn(r[j], __fmul_rn(a[i + j], a[i + j]));
    tot[h] = __fadd_rn(__fadd_rn(__fadd_rn(r[0], r[1]), __fadd_rn(r[2], r[3])),
                       __fadd_rn(__fadd_rn(r[4], r[5]), __fadd_rn(r[6], r[7])));
  }
  return __fadd_rn(tot[0], tot[1]);
}

__global__ void rowsq_np(const float* __restrict__ E, float* __restrict__ e2, int rows) {
  const int k = blockIdx.x * 256 + threadIdx.x;
  if (k < rows) e2[k] = np_sq256(E + (size_t)k * Dim);
}

// ---------------------------------------------------------------------------
// 2-limb f16 split with exact power-of-2 scaling:
//   t = v*scale (exact); hi = f16(t); lo = f16(t - hi)  (t - (f32)hi exact)
// layout: dst row = [hi(256) | lo(256)]
__global__ void split_rows(const float* __restrict__ src, f16* __restrict__ dst,
                           const float scale, const int rows)
{
  const int i   = blockIdx.x * 256 + threadIdx.x;
  const int row = i >> 6;
  const int d0  = (i & 63) * 4;
  if (row >= rows) return;
  const vf4 v = *(const vf4*)(src + (size_t)row * 256 + d0);
  f16x4 hi, lo;
  #pragma unroll
  for (int j = 0; j < 4; ++j) {
    const float t = __fmul_rn(v[j], scale);
    const f16 h   = (f16)t;
    const float r = __fsub_rn(t, (float)h);
    hi[j] = h;
    lo[j] = (f16)r;
  }
  *(f16x4*)(dst + (size_t)row * 512 + d0)       = hi;
  *(f16x4*)(dst + (size_t)row * 512 + 256 + d0) = lo;
}

// ---------------------------------------------------------------------------
// MFMA candidate pass. Grid: 2048 = 256 row-groups x 8 col-groups. Block =
// 128 rows x 512 cols (4 col-tiles of 128). Tile 128x128, 4 waves (2x2 of
// 64x64), BK=32. Virtual K = 768 as 3 segments of 8 steps:
//   seg0: A off 0   B off 0    (hiX*hiE)
//   seg1: A off 256 B off 0    (loX*hiE)
//   seg2: A off 0   B off 256  (hiX*loE)
// Staging: global_load_lds width=16 into TRIPLE-BUFFERED LDS with COUNTED
// vmcnt (T3+T4, round 8: -7%): stage(g+2) issued at step g, gate =
// s_waitcnt vmcnt(4) + raw s_barrier + sched_barrier(0); st==23 drains.
// ROUND 9: running argmin top-2 lives in LDS per (row, wc-half) — each
// cell owned exclusively by one wave (init + merge by that wave only: no
// barriers, no atomics). This removes 64 best-state VGPRs from the K-loop,
// enabling launch_bounds(256,3): cap 512/3=170 regs, 3 blocks/CU (12
// waves/CU vs 8) — occupancy was the frozen constraint across rounds 3-8
// (MfmaUtil 13%, VALU 50%, Occ 22.6% under 4 different schedules).
// LDS/block = 48K stage + 4K best = 53248 B; x3 = 159744 <= 160K.
// Fold is per-ct: per-thread 2-deep over fn, 16-lane butterfly (all lanes
// converge), lc==0 merges into LDS top-2 (stored cols < new cols -> stored
// wins ties -> numpy first-index). Exact argmin recomputed by recheck().
#define AOF(s) ((((s) >> 3) == 1 ? 256 : 0) + ((s) & 7) * 32)
#define BOF(s) ((((s) >> 3) == 2 ? 256 : 0) + ((s) & 7) * 32)
#define STAGE4(aP0, aP1, bP0, bP1, bufi)                                \
  do {                                                                  \
    GLD16((aP0), &As[(bufi)][wv * 1024]);                               \
    GLD16((aP1), &As[(bufi)][wv * 1024 + 512]);                         \
    GLD16((bP0), &Bs[(bufi)][wv * 1024]);                               \
    GLD16((bP1), &Bs[(bufi)][wv * 1024 + 512]);                         \
  } while (0)

__global__ __launch_bounds__(256, 3) void mfma_argmin(
    const f16* __restrict__ Xs, const f16* __restrict__ Es,
    const float* __restrict__ e2, const float two_scale,
    int* __restrict__ cand)
{
  __shared__ __align__(16) f16 As[3][128 * 32];
  __shared__ __align__(16) f16 Bs[3][128 * 32];
  __shared__ float bT[128][2][2];       // running top-2 value  [row][wc][rank]
  __shared__ int   bI[128][2][2];       // running top-2 index

  const int tid  = threadIdx.x;
  const int bid  = blockIdx.x;
  const int row0 = (bid >> 3) * 128;
  const int cg   = bid & 7;
  const int colbase = cg * 512;

  const int l  = tid & 63;
  const int wv = tid >> 6;
  const int wr = wv >> 1;
  const int wc = wv & 1;
  const int lc = l & 15;
  const int kc = l >> 4;

  // init wave-owned best cells (rows wr*64+l, col-half wc): no barrier needed
  bT[wr * 64 + l][wc][0] = INFINITY;  bT[wr * 64 + l][wc][1] = INFINITY;
  bI[wr * 64 + l][wc][0] = 0x7fffffff; bI[wr * 64 + l][wc][1] = 0x7fffffff;
  asm volatile("s_waitcnt lgkmcnt(0)" ::: "memory");

  // staging: wave wv stages rows [wv*32, wv*32+16) (issue0) and +16 (issue1)
  const int srow = wv * 32 + (l >> 2);
  const int chs  = (l & 3) ^ ((l >> 3) & 3);

  const f16* aB0 = Xs + (size_t)(row0 + srow) * 512 + chs * 8;
  const f16* aB1 = aB0 + 16 * 512;
  const f16* bBase0 = Es + (size_t)(colbase + srow) * 512 + chs * 8;
  const f16* bBase1 = bBase0 + 16 * 512;

  // frag-read swizzled k-slot (row = ..+lc; (row>>1)&3 == (lc>>1)&3)
  const int ks = (kc ^ ((lc >> 1) & 3)) * 8;

  const float nts = -two_scale;

  // prologue: stages 0 and 1 of ct=0 (8 loads in flight)
  STAGE4(aB0 + AOF(0), aB1 + AOF(0), bBase0 + BOF(0), bBase1 + BOF(0), 0);
  STAGE4(aB0 + AOF(1), aB1 + AOF(1), bBase0 + BOF(1), bBase1 + BOF(1), 1);

  #pragma unroll 1
  for (int ct = 0; ct < 4; ++ct) {
    const f16* bC0 = bBase0 + ct * 65536;   // + ct * 128 rows * 512 f16
    const f16* bC1 = bBase1 + ct * 65536;

    f32x4 acc[4][4];
    #pragma unroll
    for (int i = 0; i < 4; ++i)
      #pragma unroll
      for (int j = 0; j < 4; ++j)
        acc[i][j] = (f32x4){0.0f, 0.0f, 0.0f, 0.0f};

    #pragma unroll
    for (int st = 0; st < 24; ++st) {
      // gate: this step's stage complete everywhere; 4 newer loads stay
      // in flight (never drain to 0 in steady state — T4)
      if (st == 23) { asm volatile("s_waitcnt vmcnt(0)" ::: "memory"); }
      else          { asm volatile("s_waitcnt vmcnt(4)" ::: "memory"); }
      __builtin_amdgcn_s_barrier();
      __builtin_amdgcn_sched_barrier(0);

      const int cur = st % 3;
      f16x8 af[4], bf[4];
      #pragma unroll
      for (int f = 0; f < 4; ++f) {
        af[f] = *(const f16x8*)(&As[cur][(wr * 64 + f * 16 + lc) * 32 + ks]);
        bf[f] = *(const f16x8*)(&Bs[cur][(wc * 64 + f * 16 + lc) * 32 + ks]);
      }

      // issue stage(g+2) into buf (st+2)%3 (last read at step g-1: WAR-safe)
      if (st + 2 < 24) {
        STAGE4(aB0 + AOF(st + 2), aB1 + AOF(st + 2),
               bC0 + BOF(st + 2), bC1 + BOF(st + 2), (st + 2) % 3);
      } else if (ct < 3) {                  // seam: next ct's stage st-22
        STAGE4(aB0 + AOF(st - 22), aB1 + AOF(st - 22),
               bC0 + 65536 + BOF(st - 22), bC1 + 65536 + BOF(st - 22),
               (st + 2) % 3);
      }

      __builtin_amdgcn_s_setprio(1);
      #pragma unroll
      for (int fm = 0; fm < 4; ++fm)
        #pragma unroll
        for (int fn = 0; fn < 4; ++fn)
          acc[fm][fn] = __builtin_amdgcn_mfma_f32_16x16x32_f16(
              af[fm], bf[fn], acc[fm][fn], 0, 0, 0);
      __builtin_amdgcn_s_setprio(0);
    }

    // ---- per-ct fold: thread 2-deep -> 16-lane butterfly -> LDS merge ----
    float e2v[4];
    #pragma unroll
    for (int fn = 0; fn < 4; ++fn)
      e2v[fn] = e2[colbase + ct * 128 + wc * 64 + fn * 16 + lc];

    #pragma unroll
    for (int fm = 0; fm < 4; ++fm) {
      #pragma unroll
      for (int j = 0; j < 4; ++j) {
        float u1 = INFINITY, u2 = INFINITY;
        int   v1 = 0x7fffffff, v2 = 0x7fffffff;
        #pragma unroll
        for (int fn = 0; fn < 4; ++fn) {
          const int col = colbase + ct * 128 + wc * 64 + fn * 16 + lc;
          const float t = fmaf(nts, acc[fm][fn][j], e2v[fn]);
          if (t < u1) { u2 = u1; v2 = v1; u1 = t; v1 = col; }
          else if (t < u2) { u2 = t; v2 = col; }
        }
        // butterfly over the 16 lc lanes (all lanes converge)
        #pragma unroll
        for (int m = 1; m < 16; m <<= 1) {
          const float p1 = __shfl_xor(u1, m);
          const float p2 = __shfl_xor(u2, m);
          const int   q1 = __shfl_xor(v1, m);
          const int   q2 = __shfl_xor(v2, m);
          const bool pl = (p1 < u1) || (p1 == u1 && q1 < v1);
          float n1, n2; int m1, m2;
          if (pl) {
            n1 = p1; m1 = q1;
            const bool sl = (u1 < p2) || (u1 == p2 && v1 < q2);
            n2 = sl ? u1 : p2; m2 = sl ? v1 : q2;
          } else {
            n1 = u1; m1 = v1;
            const bool sl = (p1 < u2) || (p1 == u2 && q1 < v2);
            n2 = sl ? p1 : u2; m2 = sl ? q1 : v2;
          }
          u1 = n1; v1 = m1; u2 = n2; v2 = m2;
        }
        if (lc == 0) {                       // merge into wave-owned LDS cell
          const int rloc = wr * 64 + fm * 16 + kc * 4 + j;
          const float c1 = bT[rloc][wc][0], c2 = bT[rloc][wc][1];
          const int   d1 = bI[rloc][wc][0], d2 = bI[rloc][wc][1];
          const bool fn_ = (u1 < c1) || (u1 == c1 && v1 < d1);
          float r1, r2; int s1, s2;
          if (fn_) {
            r1 = u1; s1 = v1;
            const bool sl = (u2 < c1) || (u2 == c1 && v2 < d1);
            r2 = sl ? u2 : c1; s2 = sl ? v2 : d1;
          } else {
            r1 = c1; s1 = d1;
            const bool sl = (c2 < u1) || (c2 == u1 && d2 < v1);
            r2 = sl ? c2 : u1; s2 = sl ? d2 : v1;
          }
          bT[rloc][wc][0] = r1; bT[rloc][wc][1] = r2;
          bI[rloc][wc][0] = s1; bI[rloc][wc][1] = s2;
        }
      }
    }
  }

  // final: all waves' merges visible, write 4 candidates per row
  __syncthreads();
  if (tid < 128) {
    const size_t base = ((size_t)(row0 + tid) * 8 + cg) * 4;
    cand[base]     = bI[tid][0][0];
    cand[base + 1] = bI[tid][0][1];
    cand[base + 2] = bI[tid][1][0];
    cand[base + 3] = bI[tid][1][1];
  }
}

// ---------------------------------------------------------------------------
// exact recheck: for each row, recompute numpy-exact f32 distance for the 32
// candidates and take lexicographic (s, k) min — identical arithmetic to the
// previously-passing VALU kernel (serial ascending-d fmaf chain, then
// s = fl(fl(x2 - fl(2*acc)) + e2[k])), numpy first-index tie semantics.
__global__ void recheck(const float* __restrict__ X, const float* __restrict__ x2g,
                        const float* __restrict__ Eref, const float* __restrict__ e2ref,
                        const int* __restrict__ cand, int* __restrict__ idxo)
{
  __shared__ float Xl[8][256];
  const int tid  = threadIdx.x;
  const int rg   = tid >> 5;            // row within block (8 rows/block)
  const int lr   = tid & 31;            // candidate lane
  const int row0 = blockIdx.x * 8;
  const int row  = row0 + rg;

  {
    const float* xp = X + (size_t)row * 256 + lr * 8;
    *(vf4*)(&Xl[rg][lr * 8])     = *(const vf4*)xp;
    *(vf4*)(&Xl[rg][lr * 8 + 4]) = *(const vf4*)(xp + 4);
  }
  __syncthreads();

  int k = cand[(size_t)row * 32 + lr];

  float acc = 0.0f;
  const float* ep = Eref + (size_t)k * 256;
  for (int d4 = 0; d4 < 64; ++d4) {
    const vf4 xv = *(const vf4*)(&Xl[rg][d4 * 4]);
    const vf4 ev = *(const vf4*)(ep + d4 * 4);
    acc = fmaf(xv[0], ev[0], acc);
    acc = fmaf(xv[1], ev[1], acc);
    acc = fmaf(xv[2], ev[2], acc);
    acc = fmaf(xv[3], ev[3], acc);
  }
  float s = __fadd_rn(__fsub_rn(x2g[row], __fmul_rn(2.0f, acc)), e2ref[k]);

  #pragma unroll
  for (int m = 1; m < 32; m <<= 1) {
    const float os = __shfl_xor(s, m);
    const int   ok = __shfl_xor(k, m);
    if (os < s || (os == s && ok < k)) { s = os; k = ok; }
  }
  if (lr == 0) idxo[row] = k;
}

// ----------------------- counts + dw atomics + loss (no OQ/OI writes) ------
__global__ void stats_cd(const float* __restrict__ X, const float* __restrict__ E,
                         const int* __restrict__ idx, float* __restrict__ counts,
                         float* __restrict__ dw, double* __restrict__ loss_acc)
{
  __shared__ double part[4];
  const int tid  = threadIdx.x;
  const int lane = tid & 63, w = tid >> 6;
  const int row  = blockIdx.x * 4 + w;
  const int k    = idx[row];
  const vf4 xv = ((const vf4*)X)[(size_t)row * 64 + lane];
  const vf4 qv = ((const vf4*)E)[(size_t)k * 64 + lane];
  const float d0 = xv[0]-qv[0], d1 = xv[1]-qv[1], d2 = xv[2]-qv[2], d3 = xv[3]-qv[3];
  double ps = (double)(d0*d0 + d1*d1 + d2*d2 + d3*d3);
  #pragma unroll
  for (int o = 32; o; o >>= 1) ps += __shfl_down(ps, o);
  #pragma unroll
  for (int j = 0; j < 4; ++j)
    atomicAdd(dw + (size_t)k * Dim + lane * 4 + j, xv[j]);
  if (lane == 0) {
    part[w] = ps;
    atomicAdd(counts + k, 1.0f);
  }
  __syncthreads();
  if (tid == 0) atomicAdd(loss_acc, part[0] + part[1] + part[2] + part[3]);
}

// quantized gather + index write, LAST (frees OQ region for Xs during argmins)
__global__ void gather_q(const float* __restrict__ E, const int* __restrict__ idx,
                         float* __restrict__ out)
{
  const int tid  = threadIdx.x;
  const int lane = tid & 63, w = tid >> 6;
  const int row  = blockIdx.x * 4 + w;
  const int k    = idx[row];
  ((vf4*)out)[(size_t)row * 64 + lane] = ((const vf4*)E)[(size_t)k * 64 + lane];
  if (lane == 0) out[OI + row] = (float)k;
}

// ------------------------------------------------- per-code EMA scalar updates
__global__ void cs_usage(const float* __restrict__ ecs, const float* __restrict__ usage,
                         const float* __restrict__ counts, float* __restrict__ out,
                         int* __restrict__ pos_cnt)
{
  __shared__ int si[256];
  const int tid = threadIdx.x;
  const int k   = blockIdx.x * 256 + tid;
  const float cnt = counts[k];
  const float ncs = __fadd_rn(__fmul_rn(ecs[k], 0.99f), __fmul_rn(0.01f, cnt));
  out[OCS + k] = ncs;
  const float nus = __fadd_rn(__fmul_rn(usage[k], 0.99f), __fmul_rn(0.01f, cnt));
  out[OU + k] = nus;
  si[tid] = (nus > 0.0f) ? 1 : 0;
  __syncthreads();
  for (int s = 128; s; s >>= 1) {
    if (tid < s) si[tid] += si[tid + s];
    __syncthreads();
  }
  if (tid == 0) atomicAdd(pos_cnt, si[0]);
}

// n = np.sum(new_cs), numpy pairwise over 4096
__global__ void n_np_kernel(const float* __restrict__ ncs, float* __restrict__ nf) {
  __shared__ float leaf[32];
  const int t = threadIdx.x;
  if (t < 32) {
    const float* a = ncs + t * 128;
    float r[8];
    #pragma unroll
    for (int j = 0; j < 8; ++j) r[j] = a[j];
    for (int i = 8; i < 128; i += 8)
      #pragma unroll
      for (int j = 0; j < 8; ++j) r[j] = __fadd_rn(r[j], a[i + j]);
    leaf[t] = __fadd_rn(__fadd_rn(__fadd_rn(r[0], r[1]), __fadd_rn(r[2], r[3])),
                        __fadd_rn(__fadd_rn(r[4], r[5]), __fadd_rn(r[6], r[7])));
  }
  __syncthreads();
  if (t == 0) {
    float v[32];
    #pragma unroll
    for (int i = 0; i < 32; ++i) v[i] = leaf[i];
    for (int n = 32; n > 1; n >>= 1)
      for (int i = 0; i < (n >> 1); ++i) v[i] = __fadd_rn(v[2 * i], v[2 * i + 1]);
    *nf = v[0];
  }
}

// new_ema_w (in place over dw accum) and pre-embedding (written to out[OE];
// all consumers of the pre-reset embedding run before finalize_k), numpy order
__global__ void emb_pre(const float* __restrict__ emaw, float* __restrict__ out,
                        const float* __restrict__ nf)
{
  const int k = blockIdx.x;
  const int d = threadIdx.x;
  const size_t o = (size_t)k * Dim + d;
  const float dwv = out[OW + o];
  const float w = __fadd_rn(__fmul_rn(emaw[o], 0.99f), __fmul_rn(0.01f, dwv));
  out[OW + o] = w;
  const float nv  = *nf;
  const float ncs = out[OCS + k];
  const float cs  = __fmul_rn(__fdiv_rn(__fadd_rn(ncs, EPSf), __fadd_rn(nv, KEPSf)), nv);
  out[OE + o] = __fdiv_rn(w, cs);
}

__global__ void used_scatter(const int* __restrict__ idx2, int* __restrict__ used) {
  const int i = blockIdx.x * 256 + threadIdx.x;
  used[idx2[i]] = 1;
}

__global__ void finalize_k(const float* __restrict__ X, const int* __restrict__ used,
                           const int* __restrict__ steps_in, const int* __restrict__ rnd,
                           float* __restrict__ out)
{
  const int k = blockIdx.x, d = threadIdx.x;
  const int u = used[k];
  const float st = u ? 0.0f : (float)steps_in[k] + 1.0f;
  const bool dead = st > 100.0f;
  if (dead) out[OE + (size_t)k * Dim + d] = X[(size_t)rnd[k] * Dim + d];
  if (d == 0) out[OS + k] = dead ? 0.0f : st;
}

__global__ void write_scalars(const double* __restrict__ loss_acc,
                              const int* __restrict__ pos_cnt, float* __restrict__ out)
{
  if (threadIdx.x == 0) {
    out[OL] = 0.25f * (float)(*loss_acc / (double)((size_t)Ncnt * Dim));
    out[OR] = (float)(*pos_cnt) / (float)Kcb;
  }
}

// ---------------------------------------------------------------------- launch
extern "C" void kernel_launch(void* const* d_in, const int* in_sizes, int n_in,
                              void* d_out, int out_size, void* d_ws, size_t ws_size,
                              hipStream_t stream)
{
  const float* X     = (const float*)d_in[0];
  const float* E     = (const float*)d_in[1];
  const float* ECS   = (const float*)d_in[2];
  const float* EMAW  = (const float*)d_in[3];
  const float* USAGE = (const float*)d_in[4];
  const int*   STEPS = (const int*)d_in[5];
  const int*   RND   = (const int*)d_in[6];
  float* out = (float*)d_out;

  float* wsf = (float*)d_ws;
  float*  counts   = wsf;                          // [4096]  zeroed
  int*    used     = (int*)(wsf + 4096);           // [4096]  zeroed
  double* loss_acc = (double*)(wsf + 8192);        //         zeroed
  float*  nf       = wsf + 8194;
  int*    pos_cnt  = (int*)(wsf + 8195);
  const size_t ZN  = 8200;                         // zero region, floats
  float* x2g  = wsf + 8320;                        // [32768]          -> 41088
  float* e2   = wsf + 41088;                       // [4096]           -> 45184
  float* e2p  = wsf + 45184;                       // [4096]           -> 49280
  int*   idx1 = (int*)(wsf + 49280);               // [32768]          -> 82048
  int*   idx2 = (int*)(wsf + 82048);               // [32768]          -> 114816
  f16*   Es   = (f16*)(wsf + 114816);              // 4096*512 f16 = 1048576 f -> 1163392
  int*   cand = (int*)(wsf + 1163392);             // 32768*32 ints    -> 2211968
  // pre-reset embedding lives directly in out[OE] (consumers run pre-reset).
  // Xs (32768x512 f16 = 32 MiB) parks exactly in the OQ output region;
  // gather_q rewrites OQ after the second argmin is done.
  f16*   Xsp  = (f16*)out;

  hipMemsetAsync(d_ws, 0, ZN * sizeof(float), stream);
  hipMemsetAsync(out + OW, 0, (size_t)Kcb * Dim * sizeof(float), stream); // dw accum

  rowsq_np     <<<Ncnt / 256, 256, 0, stream>>>(X, x2g, Ncnt);
  rowsq_np     <<<Kcb / 256,  256, 0, stream>>>(E, e2, Kcb);
  split_rows   <<<Ncnt / 4,   256, 0, stream>>>(X, Xsp, 64.0f, Ncnt);      // 2^6
  split_rows   <<<Kcb / 4,    256, 0, stream>>>(E, Es, 16777216.0f, Kcb);  // 2^24
  mfma_argmin  <<<2048,       256, 0, stream>>>(Xsp, Es, e2, 0x1p-29f, cand);
  recheck      <<<Ncnt / 8,   256, 0, stream>>>(X, x2g, E, e2, cand, idx1);
  stats_cd     <<<Ncnt / 4,   256, 0, stream>>>(X, E, idx1, counts, out + OW, loss_acc);
  cs_usage     <<<Kcb / 256,  256, 0, stream>>>(ECS, USAGE, counts, out, pos_cnt);
  n_np_kernel  <<<1,          64,  0, stream>>>(out + OCS, nf);
  emb_pre      <<<Kcb,        256, 0, stream>>>(EMAW, out, nf);
  rowsq_np     <<<Kcb / 256,  256, 0, stream>>>(out + OE, e2p, Kcb);
  split_rows   <<<Kcb / 4,    256, 0, stream>>>(out + OE, Es, 256.0f, Kcb); // 2^8
  mfma_argmin  <<<2048,       256, 0, stream>>>(Xsp, Es, e2p, 0x1p-13f, cand);
  recheck      <<<Ncnt / 8,   256, 0, stream>>>(X, x2g, out + OE, e2p, cand, idx2);
  used_scatter <<<Ncnt / 256, 256, 0, stream>>>(idx2, used);
  finalize_k   <<<Kcb,        256, 0, stream>>>(X, used, STEPS, RND, out);
  gather_q     <<<Ncnt / 4,   256, 0, stream>>>(E, idx1, out);
  write_scalars<<<1,          64,  0, stream>>>(loss_acc, pos_cnt, out);

  (void)in_sizes; (void)n_in; (void)out_size; (void)ws_size;
}

// Round 10
// 1697.868 us; speedup vs baseline: 4.3170x; 1.0124x over previous
//
#include <hip/hip_runtime.h>
#include <math.h>

typedef float vf4 __attribute__((ext_vector_type(4)));
typedef _Float16 f16;
typedef _Float16 f16x8 __attribute__((ext_vector_type(8)));
typedef _Float16 f16x4 __attribute__((ext_vector_type(4)));
typedef float f32x4 __attribute__((ext_vector_type(4)));

static constexpr int Ncnt = 32768;
static constexpr int Kcb  = 4096;
static constexpr int Dim  = 256;

static constexpr float EPSf  = 1e-5f;
static constexpr float KEPSf = (float)(4096.0 * 1e-5);

// d_out float offsets (reference return order, flattened)
static constexpr size_t OQ  = 0;
static constexpr size_t OI  = (size_t)Ncnt * Dim;
static constexpr size_t OL  = OI + Ncnt;
static constexpr size_t OE  = OL + 1;
static constexpr size_t OCS = OE + (size_t)Kcb * Dim;
static constexpr size_t OW  = OCS + Kcb;
static constexpr size_t OU  = OW + (size_t)Kcb * Dim;
static constexpr size_t OS  = OU + Kcb;
static constexpr size_t OR  = OS + Kcb;

// async global->LDS, 16B per lane; LDS dest is wave-uniform base + lane*16
#define GLD16(gp, lp)                                                   \
  __builtin_amdgcn_global_load_lds(                                     \
      (const __attribute__((address_space(1))) void*)(gp),              \
      (__attribute__((address_space(3))) void*)(lp), 16, 0, 0)

// ---------------------------------------------------------------------------
// numpy pairwise_sum over fl(p[i]*p[i]) for n=256 (bit-exact np.sum(x*x,1))
__device__ __forceinline__ float np_sq256(const float* __restrict__ p) {
  float tot[2];
  #pragma unroll
  for (int h = 0; h < 2; ++h) {
    const float* a = p + h * 128;
    float r[8];
    #pragma unroll
    for (int j = 0; j < 8; ++j) r[j] = __fmul_rn(a[j], a[j]);
    for (int i = 8; i < 128; i += 8)
      #pragma unroll
      for (int j = 0; j < 8; ++j) r[j] = __fadd_rn(r[j], __fmul_rn(a[i + j], a[i + j]));
    tot[h] = __fadd_rn(__fadd_rn(__fadd_rn(r[0], r[1]), __fadd_rn(r[2], r[3])),
                       __fadd_rn(__fadd_rn(r[4], r[5]), __fadd_rn(r[6], r[7])));
  }
  return __fadd_rn(tot[0], tot[1]);
}

__global__ void rowsq_np(const float* __restrict__ E, float* __restrict__ e2, int rows) {
  const int k = blockIdx.x * 256 + threadIdx.x;
  if (k < rows) e2[k] = np_sq256(E + (size_t)k * Dim);
}

// ---------------------------------------------------------------------------
// 2-limb f16 split with exact power-of-2 scaling:
//   t = v*scale (exact); hi = f16(t); lo = f16(t - hi)  (t - (f32)hi exact)
// layout: dst row = [hi(256) | lo(256)]
__global__ void split_rows(const float* __restrict__ src, f16* __restrict__ dst,
                           const float scale, const int rows)
{
  const int i   = blockIdx.x * 256 + threadIdx.x;
  const int row = i >> 6;
  const int d0  = (i & 63) * 4;
  if (row >= rows) return;
  const vf4 v = *(const vf4*)(src + (size_t)row * 256 + d0);
  f16x4 hi, lo;
  #pragma unroll
  for (int j = 0; j < 4; ++j) {
    const float t = __fmul_rn(v[j], scale);
    const f16 h   = (f16)t;
    const float r = __fsub_rn(t, (float)h);
    hi[j] = h;
    lo[j] = (f16)r;
  }
  *(f16x4*)(dst + (size_t)row * 512 + d0)       = hi;
  *(f16x4*)(dst + (size_t)row * 512 + 256 + d0) = lo;
}

// ---------------------------------------------------------------------------
// MFMA candidate pass. Grid: 2048 = 256 row-groups x 8 col-groups. Block =
// 128 rows x 512 cols (4 col-tiles of 128). Tile 128x128, 4 waves (2x2 of
// 64x64), BK=32. Virtual K = 768 as 3 segments of 8 steps:
//   seg0: A off 0   B off 0    (hiX*hiE)
//   seg1: A off 256 B off 0    (loX*hiE)
//   seg2: A off 0   B off 256  (hiX*loE)
// ROUND 10: 4 blocks/CU. DOUBLE-buffered stage LDS (36864 B/block; x4 =
// 147456 <= 160K) with depth-2 counted-vmcnt kept: stage(st+2) is issued
// AFTER a non-draining barrier2 (lgkmcnt(0) + raw s_barrier) that proves
// all waves finished reading buf[st&1] this step -> WAR-safe to overwrite
// the just-read buffer; it is consumed 2 iterations later (issue->consume
// ~2 steps, covers HBM latency). Gate: s_waitcnt vmcnt(4) + s_barrier +
// sched_barrier(0); outstanding at gate = stages (st),(st+1) = 8, wait-4
// retires stage(st). Only ct==3,st==23 (no further issues) needs vmcnt(0).
// launch_bounds(256,4): cap 128 on unified VGPR+AGPR. Live ~121 (64 acc +
// 32 frags + addr) -> expected fit; spill signature = WRITE_SIZE in GBs
// (round-5 lesson) -> revert to (256,3) if seen.
// Running argmin top-2 in LDS per (row, wc-half), wave-owned (round 9).
// LDS dest linear; global source chunk pre-swizzled chs = (l&3)^((l>>3)&3);
// frag reads use slot ks = (kc ^ ((lc>>1)&3))*8 (proven involution).
// Proxy t = fmaf(-two_scale, acc, e2[col]); exact argmin via recheck().
#define AOF(s) ((((s) >> 3) == 1 ? 256 : 0) + ((s) & 7) * 32)
#define BOF(s) ((((s) >> 3) == 2 ? 256 : 0) + ((s) & 7) * 32)
#define STAGE4(aP0, aP1, bP0, bP1, bufi)                                \
  do {                                                                  \
    GLD16((aP0), &As[(bufi)][wv * 1024]);                               \
    GLD16((aP1), &As[(bufi)][wv * 1024 + 512]);                         \
    GLD16((bP0), &Bs[(bufi)][wv * 1024]);                               \
    GLD16((bP1), &Bs[(bufi)][wv * 1024 + 512]);                         \
  } while (0)

__global__ __launch_bounds__(256, 4) void mfma_argmin(
    const f16* __restrict__ Xs, const f16* __restrict__ Es,
    const float* __restrict__ e2, const float two_scale,
    int* __restrict__ cand)
{
  __shared__ __align__(16) f16 As[2][128 * 32];
  __shared__ __align__(16) f16 Bs[2][128 * 32];
  __shared__ float bT[128][2][2];       // running top-2 value  [row][wc][rank]
  __shared__ int   bI[128][2][2];       // running top-2 index

  const int tid  = threadIdx.x;
  const int bid  = blockIdx.x;
  const int row0 = (bid >> 3) * 128;
  const int cg   = bid & 7;
  const int colbase = cg * 512;

  const int l  = tid & 63;
  const int wv = tid >> 6;
  const int wr = wv >> 1;
  const int wc = wv & 1;
  const int lc = l & 15;
  const int kc = l >> 4;

  // init wave-owned best cells (rows wr*64+l, col-half wc): no barrier needed
  bT[wr * 64 + l][wc][0] = INFINITY;  bT[wr * 64 + l][wc][1] = INFINITY;
  bI[wr * 64 + l][wc][0] = 0x7fffffff; bI[wr * 64 + l][wc][1] = 0x7fffffff;
  asm volatile("s_waitcnt lgkmcnt(0)" ::: "memory");

  // staging: wave wv stages rows [wv*32, wv*32+16) (issue0) and +16 (issue1)
  const int srow = wv * 32 + (l >> 2);
  const int chs  = (l & 3) ^ ((l >> 3) & 3);

  const f16* aB0 = Xs + (size_t)(row0 + srow) * 512 + chs * 8;
  const f16* aB1 = aB0 + 16 * 512;
  const f16* bBase0 = Es + (size_t)(colbase + srow) * 512 + chs * 8;
  const f16* bBase1 = bBase0 + 16 * 512;

  // frag-read swizzled k-slot (row = ..+lc; (row>>1)&3 == (lc>>1)&3)
  const int ks = (kc ^ ((lc >> 1) & 3)) * 8;

  const float nts = -two_scale;

  // prologue: stages 0 and 1 of ct=0 (8 loads in flight)
  STAGE4(aB0 + AOF(0), aB1 + AOF(0), bBase0 + BOF(0), bBase1 + BOF(0), 0);
  STAGE4(aB0 + AOF(1), aB1 + AOF(1), bBase0 + BOF(1), bBase1 + BOF(1), 1);

  #pragma unroll 1
  for (int ct = 0; ct < 4; ++ct) {
    const f16* bC0 = bBase0 + ct * 65536;   // + ct * 128 rows * 512 f16
    const f16* bC1 = bBase1 + ct * 65536;

    f32x4 acc[4][4];
    #pragma unroll
    for (int i = 0; i < 4; ++i)
      #pragma unroll
      for (int j = 0; j < 4; ++j)
        acc[i][j] = (f32x4){0.0f, 0.0f, 0.0f, 0.0f};

    #pragma unroll
    for (int st = 0; st < 24; ++st) {
      // gate: stage(st) complete everywhere; stage(st+1) stays in flight.
      // Only the very last step of the kernel has <8 outstanding.
      if (st == 23) {
        if (ct == 3) { asm volatile("s_waitcnt vmcnt(0)" ::: "memory"); }
        else         { asm volatile("s_waitcnt vmcnt(4)" ::: "memory"); }
      } else         { asm volatile("s_waitcnt vmcnt(4)" ::: "memory"); }
      __builtin_amdgcn_s_barrier();
      __builtin_amdgcn_sched_barrier(0);

      const int cur = st & 1;
      f16x8 af[4], bf[4];
      #pragma unroll
      for (int f = 0; f < 4; ++f) {
        af[f] = *(const f16x8*)(&As[cur][(wr * 64 + f * 16 + lc) * 32 + ks]);
        bf[f] = *(const f16x8*)(&Bs[cur][(wc * 64 + f * 16 + lc) * 32 + ks]);
      }

      // barrier2 (non-draining): all waves' frag reads of buf[cur] done ->
      // WAR-safe to overwrite buf[cur] with stage(st+2)
      asm volatile("s_waitcnt lgkmcnt(0)" ::: "memory");
      __builtin_amdgcn_s_barrier();
      __builtin_amdgcn_sched_barrier(0);

      // issue stage(st+2) into buf[cur]; consumed 2 iterations later
      if (st + 2 < 24) {
        STAGE4(aB0 + AOF(st + 2), aB1 + AOF(st + 2),
               bC0 + BOF(st + 2), bC1 + BOF(st + 2), cur);
      } else if (ct < 3) {                  // seam: next ct's stage st-22
        STAGE4(aB0 + AOF(st - 22), aB1 + AOF(st - 22),
               bC0 + 65536 + BOF(st - 22), bC1 + 65536 + BOF(st - 22),
               cur);
      }

      __builtin_amdgcn_s_setprio(1);
      #pragma unroll
      for (int fm = 0; fm < 4; ++fm)
        #pragma unroll
        for (int fn = 0; fn < 4; ++fn)
          acc[fm][fn] = __builtin_amdgcn_mfma_f32_16x16x32_f16(
              af[fm], bf[fn], acc[fm][fn], 0, 0, 0);
      __builtin_amdgcn_s_setprio(0);
    }

    // ---- per-ct fold: thread 2-deep -> 16-lane butterfly -> LDS merge ----
    float e2v[4];
    #pragma unroll
    for (int fn = 0; fn < 4; ++fn)
      e2v[fn] = e2[colbase + ct * 128 + wc * 64 + fn * 16 + lc];

    #pragma unroll
    for (int fm = 0; fm < 4; ++fm) {
      #pragma unroll
      for (int j = 0; j < 4; ++j) {
        float u1 = INFINITY, u2 = INFINITY;
        int   v1 = 0x7fffffff, v2 = 0x7fffffff;
        #pragma unroll
        for (int fn = 0; fn < 4; ++fn) {
          const int col = colbase + ct * 128 + wc * 64 + fn * 16 + lc;
          const float t = fmaf(nts, acc[fm][fn][j], e2v[fn]);
          if (t < u1) { u2 = u1; v2 = v1; u1 = t; v1 = col; }
          else if (t < u2) { u2 = t; v2 = col; }
        }
        // butterfly over the 16 lc lanes (all lanes converge)
        #pragma unroll
        for (int m = 1; m < 16; m <<= 1) {
          const float p1 = __shfl_xor(u1, m);
          const float p2 = __shfl_xor(u2, m);
          const int   q1 = __shfl_xor(v1, m);
          const int   q2 = __shfl_xor(v2, m);
          const bool pl = (p1 < u1) || (p1 == u1 && q1 < v1);
          float n1, n2; int m1, m2;
          if (pl) {
            n1 = p1; m1 = q1;
            const bool sl = (u1 < p2) || (u1 == p2 && v1 < q2);
            n2 = sl ? u1 : p2; m2 = sl ? v1 : q2;
          } else {
            n1 = u1; m1 = v1;
            const bool sl = (p1 < u2) || (p1 == u2 && q1 < v2);
            n2 = sl ? p1 : u2; m2 = sl ? q1 : v2;
          }
          u1 = n1; v1 = m1; u2 = n2; v2 = m2;
        }
        if (lc == 0) {                       // merge into wave-owned LDS cell
          const int rloc = wr * 64 + fm * 16 + kc * 4 + j;
          const float c1 = bT[rloc][wc][0], c2 = bT[rloc][wc][1];
          const int   d1 = bI[rloc][wc][0], d2 = bI[rloc][wc][1];
          const bool fn_ = (u1 < c1) || (u1 == c1 && v1 < d1);
          float r1, r2; int s1, s2;
          if (fn_) {
            r1 = u1; s1 = v1;
            const bool sl = (u2 < c1) || (u2 == c1 && v2 < d1);
            r2 = sl ? u2 : c1; s2 = sl ? v2 : d1;
          } else {
            r1 = c1; s1 = d1;
            const bool sl = (c2 < u1) || (c2 == u1 && d2 < v1);
            r2 = sl ? c2 : u1; s2 = sl ? d2 : v1;
          }
          bT[rloc][wc][0] = r1; bT[rloc][wc][1] = r2;
          bI[rloc][wc][0] = s1; bI[rloc][wc][1] = s2;
        }
      }
    }
  }

  // final: all waves' merges visible, write 4 candidates per row
  __syncthreads();
  if (tid < 128) {
    const size_t base = ((size_t)(row0 + tid) * 8 + cg) * 4;
    cand[base]     = bI[tid][0][0];
    cand[base + 1] = bI[tid][0][1];
    cand[base + 2] = bI[tid][1][0];
    cand[base + 3] = bI[tid][1][1];
  }
}

// ---------------------------------------------------------------------------
// exact recheck: for each row, recompute numpy-exact f32 distance for the 32
// candidates and take lexicographic (s, k) min — identical arithmetic to the
// previously-passing VALU kernel (serial ascending-d fmaf chain, then
// s = fl(fl(x2 - fl(2*acc)) + e2[k])), numpy first-index tie semantics.
__global__ void recheck(const float* __restrict__ X, const float* __restrict__ x2g,
                        const float* __restrict__ Eref, const float* __restrict__ e2ref,
                        const int* __restrict__ cand, int* __restrict__ idxo)
{
  __shared__ float Xl[8][256];
  const int tid  = threadIdx.x;
  const int rg   = tid >> 5;            // row within block (8 rows/block)
  const int lr   = tid & 31;            // candidate lane
  const int row0 = blockIdx.x * 8;
  const int row  = row0 + rg;

  {
    const float* xp = X + (size_t)row * 256 + lr * 8;
    *(vf4*)(&Xl[rg][lr * 8])     = *(const vf4*)xp;
    *(vf4*)(&Xl[rg][lr * 8 + 4]) = *(const vf4*)(xp + 4);
  }
  __syncthreads();

  int k = cand[(size_t)row * 32 + lr];

  float acc = 0.0f;
  const float* ep = Eref + (size_t)k * 256;
  for (int d4 = 0; d4 < 64; ++d4) {
    const vf4 xv = *(const vf4*)(&Xl[rg][d4 * 4]);
    const vf4 ev = *(const vf4*)(ep + d4 * 4);
    acc = fmaf(xv[0], ev[0], acc);
    acc = fmaf(xv[1], ev[1], acc);
    acc = fmaf(xv[2], ev[2], acc);
    acc = fmaf(xv[3], ev[3], acc);
  }
  float s = __fadd_rn(__fsub_rn(x2g[row], __fmul_rn(2.0f, acc)), e2ref[k]);

  #pragma unroll
  for (int m = 1; m < 32; m <<= 1) {
    const float os = __shfl_xor(s, m);
    const int   ok = __shfl_xor(k, m);
    if (os < s || (os == s && ok < k)) { s = os; k = ok; }
  }
  if (lr == 0) idxo[row] = k;
}

// ----------------------- counts + dw atomics + loss (no OQ/OI writes) ------
__global__ void stats_cd(const float* __restrict__ X, const float* __restrict__ E,
                         const int* __restrict__ idx, float* __restrict__ counts,
                         float* __restrict__ dw, double* __restrict__ loss_acc)
{
  __shared__ double part[4];
  const int tid  = threadIdx.x;
  const int lane = tid & 63, w = tid >> 6;
  const int row  = blockIdx.x * 4 + w;
  const int k    = idx[row];
  const vf4 xv = ((const vf4*)X)[(size_t)row * 64 + lane];
  const vf4 qv = ((const vf4*)E)[(size_t)k * 64 + lane];
  const float d0 = xv[0]-qv[0], d1 = xv[1]-qv[1], d2 = xv[2]-qv[2], d3 = xv[3]-qv[3];
  double ps = (double)(d0*d0 + d1*d1 + d2*d2 + d3*d3);
  #pragma unroll
  for (int o = 32; o; o >>= 1) ps += __shfl_down(ps, o);
  #pragma unroll
  for (int j = 0; j < 4; ++j)
    atomicAdd(dw + (size_t)k * Dim + lane * 4 + j, xv[j]);
  if (lane == 0) {
    part[w] = ps;
    atomicAdd(counts + k, 1.0f);
  }
  __syncthreads();
  if (tid == 0) atomicAdd(loss_acc, part[0] + part[1] + part[2] + part[3]);
}

// quantized gather + index write, LAST (frees OQ region for Xs during argmins)
__global__ void gather_q(const float* __restrict__ E, const int* __restrict__ idx,
                         float* __restrict__ out)
{
  const int tid  = threadIdx.x;
  const int lane = tid & 63, w = tid >> 6;
  const int row  = blockIdx.x * 4 + w;
  const int k    = idx[row];
  ((vf4*)out)[(size_t)row * 64 + lane] = ((const vf4*)E)[(size_t)k * 64 + lane];
  if (lane == 0) out[OI + row] = (float)k;
}

// ------------------------------------------------- per-code EMA scalar updates
__global__ void cs_usage(const float* __restrict__ ecs, const float* __restrict__ usage,
                         const float* __restrict__ counts, float* __restrict__ out,
                         int* __restrict__ pos_cnt)
{
  __shared__ int si[256];
  const int tid = threadIdx.x;
  const int k   = blockIdx.x * 256 + tid;
  const float cnt = counts[k];
  const float ncs = __fadd_rn(__fmul_rn(ecs[k], 0.99f), __fmul_rn(0.01f, cnt));
  out[OCS + k] = ncs;
  const float nus = __fadd_rn(__fmul_rn(usage[k], 0.99f), __fmul_rn(0.01f, cnt));
  out[OU + k] = nus;
  si[tid] = (nus > 0.0f) ? 1 : 0;
  __syncthreads();
  for (int s = 128; s; s >>= 1) {
    if (tid < s) si[tid] += si[tid + s];
    __syncthreads();
  }
  if (tid == 0) atomicAdd(pos_cnt, si[0]);
}

// n = np.sum(new_cs), numpy pairwise over 4096
__global__ void n_np_kernel(const float* __restrict__ ncs, float* __restrict__ nf) {
  __shared__ float leaf[32];
  const int t = threadIdx.x;
  if (t < 32) {
    const float* a = ncs + t * 128;
    float r[8];
    #pragma unroll
    for (int j = 0; j < 8; ++j) r[j] = a[j];
    for (int i = 8; i < 128; i += 8)
      #pragma unroll
      for (int j = 0; j < 8; ++j) r[j] = __fadd_rn(r[j], a[i + j]);
    leaf[t] = __fadd_rn(__fadd_rn(__fadd_rn(r[0], r[1]), __fadd_rn(r[2], r[3])),
                        __fadd_rn(__fadd_rn(r[4], r[5]), __fadd_rn(r[6], r[7])));
  }
  __syncthreads();
  if (t == 0) {
    float v[32];
    #pragma unroll
    for (int i = 0; i < 32; ++i) v[i] = leaf[i];
    for (int n = 32; n > 1; n >>= 1)
      for (int i = 0; i < (n >> 1); ++i) v[i] = __fadd_rn(v[2 * i], v[2 * i + 1]);
    *nf = v[0];
  }
}

// new_ema_w (in place over dw accum) and pre-embedding (written to out[OE];
// all consumers of the pre-reset embedding run before finalize_k), numpy order
__global__ void emb_pre(const float* __restrict__ emaw, float* __restrict__ out,
                        const float* __restrict__ nf)
{
  const int k = blockIdx.x;
  const int d = threadIdx.x;
  const size_t o = (size_t)k * Dim + d;
  const float dwv = out[OW + o];
  const float w = __fadd_rn(__fmul_rn(emaw[o], 0.99f), __fmul_rn(0.01f, dwv));
  out[OW + o] = w;
  const float nv  = *nf;
  const float ncs = out[OCS + k];
  const float cs  = __fmul_rn(__fdiv_rn(__fadd_rn(ncs, EPSf), __fadd_rn(nv, KEPSf)), nv);
  out[OE + o] = __fdiv_rn(w, cs);
}

__global__ void used_scatter(const int* __restrict__ idx2, int* __restrict__ used) {
  const int i = blockIdx.x * 256 + threadIdx.x;
  used[idx2[i]] = 1;
}

__global__ void finalize_k(const float* __restrict__ X, const int* __restrict__ used,
                           const int* __restrict__ steps_in, const int* __restrict__ rnd,
                           float* __restrict__ out)
{
  const int k = blockIdx.x, d = threadIdx.x;
  const int u = used[k];
  const float st = u ? 0.0f : (float)steps_in[k] + 1.0f;
  const bool dead = st > 100.0f;
  if (dead) out[OE + (size_t)k * Dim + d] = X[(size_t)rnd[k] * Dim + d];
  if (d == 0) out[OS + k] = dead ? 0.0f : st;
}

__global__ void write_scalars(const double* __restrict__ loss_acc,
                              const int* __restrict__ pos_cnt, float* __restrict__ out)
{
  if (threadIdx.x == 0) {
    out[OL] = 0.25f * (float)(*loss_acc / (double)((size_t)Ncnt * Dim));
    out[OR] = (float)(*pos_cnt) / (float)Kcb;
  }
}

// ---------------------------------------------------------------------- launch
extern "C" void kernel_launch(void* const* d_in, const int* in_sizes, int n_in,
                              void* d_out, int out_size, void* d_ws, size_t ws_size,
                              hipStream_t stream)
{
  const float* X     = (const float*)d_in[0];
  const float* E     = (const float*)d_in[1];
  const float* ECS   = (const float*)d_in[2];
  const float* EMAW  = (const float*)d_in[3];
  const float* USAGE = (const float*)d_in[4];
  const int*   STEPS = (const int*)d_in[5];
  const int*   RND   = (const int*)d_in[6];
  float* out = (float*)d_out;

  float* wsf = (float*)d_ws;
  float*  counts   = wsf;                          // [4096]  zeroed
  int*    used     = (int*)(wsf + 4096);           // [4096]  zeroed
  double* loss_acc = (double*)(wsf + 8192);        //         zeroed
  float*  nf       = wsf + 8194;
  int*    pos_cnt  = (int*)(wsf + 8195);
  const size_t ZN  = 8200;                         // zero region, floats
  float* x2g  = wsf + 8320;                        // [32768]          -> 41088
  float* e2   = wsf + 41088;                       // [4096]           -> 45184
  float* e2p  = wsf + 45184;                       // [4096]           -> 49280
  int*   idx1 = (int*)(wsf + 49280);               // [32768]          -> 82048
  int*   idx2 = (int*)(wsf + 82048);               // [32768]          -> 114816
  f16*   Es   = (f16*)(wsf + 114816);              // 4096*512 f16 = 1048576 f -> 1163392
  int*   cand = (int*)(wsf + 1163392);             // 32768*32 ints    -> 2211968
  // pre-reset embedding lives directly in out[OE] (consumers run pre-reset).
  // Xs (32768x512 f16 = 32 MiB) parks exactly in the OQ output region;
  // gather_q rewrites OQ after the second argmin is done.
  f16*   Xsp  = (f16*)out;

  hipMemsetAsync(d_ws, 0, ZN * sizeof(float), stream);
  hipMemsetAsync(out + OW, 0, (size_t)Kcb * Dim * sizeof(float), stream); // dw accum

  rowsq_np     <<<Ncnt / 256, 256, 0, stream>>>(X, x2g, Ncnt);
  rowsq_np     <<<Kcb / 256,  256, 0, stream>>>(E, e2, Kcb);
  split_rows   <<<Ncnt / 4,   256, 0, stream>>>(X, Xsp, 64.0f, Ncnt);      // 2^6
  split_rows   <<<Kcb / 4,    256, 0, stream>>>(E, Es, 16777216.0f, Kcb);  // 2^24
  mfma_argmin  <<<2048,       256, 0, stream>>>(Xsp, Es, e2, 0x1p-29f, cand);
  recheck      <<<Ncnt / 8,   256, 0, stream>>>(X, x2g, E, e2, cand, idx1);
  stats_cd     <<<Ncnt / 4,   256, 0, stream>>>(X, E, idx1, counts, out + OW, loss_acc);
  cs_usage     <<<Kcb / 256,  256, 0, stream>>>(ECS, USAGE, counts, out, pos_cnt);
  n_np_kernel  <<<1,          64,  0, stream>>>(out + OCS, nf);
  emb_pre      <<<Kcb,        256, 0, stream>>>(EMAW, out, nf);
  rowsq_np     <<<Kcb / 256,  256, 0, stream>>>(out + OE, e2p, Kcb);
  split_rows   <<<Kcb / 4,    256, 0, stream>>>(out + OE, Es, 256.0f, Kcb); // 2^8
  mfma_argmin  <<<2048,       256, 0, stream>>>(Xsp, Es, e2p, 0x1p-13f, cand);
  recheck      <<<Ncnt / 8,   256, 0, stream>>>(X, x2g, out + OE, e2p, cand, idx2);
  used_scatter <<<Ncnt / 256, 256, 0, stream>>>(idx2, used);
  finalize_k   <<<Kcb,        256, 0, stream>>>(X, used, STEPS, RND, out);
  gather_q     <<<Ncnt / 4,   256, 0, stream>>>(E, idx1, out);
  write_scalars<<<1,          64,  0, stream>>>(loss_acc, pos_cnt, out);

  (void)in_sizes; (void)n_in; (void)out_size; (void)ws_size;
}

// Round 11
// 1678.827 us; speedup vs baseline: 4.3659x; 1.0113x over previous
//
#include <hip/hip_runtime.h>
#include <math.h>

typedef float vf4 __attribute__((ext_vector_type(4)));
typedef _Float16 f16;
typedef _Float16 f16x8 __attribute__((ext_vector_type(8)));
typedef _Float16 f16x4 __attribute__((ext_vector_type(4)));
typedef float f32x4 __attribute__((ext_vector_type(4)));

static constexpr int Ncnt = 32768;
static constexpr int Kcb  = 4096;
static constexpr int Dim  = 256;

static constexpr float EPSf  = 1e-5f;
static constexpr float KEPSf = (float)(4096.0 * 1e-5);

// d_out float offsets (reference return order, flattened)
static constexpr size_t OQ  = 0;
static constexpr size_t OI  = (size_t)Ncnt * Dim;
static constexpr size_t OL  = OI + Ncnt;
static constexpr size_t OE  = OL + 1;
static constexpr size_t OCS = OE + (size_t)Kcb * Dim;
static constexpr size_t OW  = OCS + Kcb;
static constexpr size_t OU  = OW + (size_t)Kcb * Dim;
static constexpr size_t OS  = OU + Kcb;
static constexpr size_t OR  = OS + Kcb;

// async global->LDS, 16B per lane; LDS dest is wave-uniform base + lane*16
#define GLD16(gp, lp)                                                   \
  __builtin_amdgcn_global_load_lds(                                     \
      (const __attribute__((address_space(1))) void*)(gp),              \
      (__attribute__((address_space(3))) void*)(lp), 16, 0, 0)

// np pairwise combine of 8 leaf chains: ((r0+r1)+(r2+r3))+((r4+r5)+(r6+r7))
__device__ __forceinline__ float np_comb8(const float* r) {
  return __fadd_rn(__fadd_rn(__fadd_rn(r[0], r[1]), __fadd_rn(r[2], r[3])),
                   __fadd_rn(__fadd_rn(r[4], r[5]), __fadd_rn(r[6], r[7])));
}

// ---------------------------------------------------------------------------
// FUSED rowsq + 2-limb split. 4 rows/block (one wave per row). Per row:
// load vf4 (4 elems/lane), write hi/lo f16x4 (split_rows layout [hi|lo]),
// stage row in LDS, then 16 lanes compute np_sq256's 16 chains (half h =
// lane>>3, slot j = lane&7: r = fl(a[j]^2); r = fl(r + fl(a[i+j]^2)) for
// i = 8..120 step 8) — bit-identical order to the serial np_sq256 — and
// lane 0 applies the exact combine tree. split: t = v*scale (exact pow2);
// hi = f16(t); lo = f16(fl(t - (f32)hi)).
__global__ void rs_fused(const float* __restrict__ src, f16* __restrict__ dst,
                         const float scale, float* __restrict__ sq)
{
  __shared__ float Xl[4][256];
  __shared__ float scr[4][16];
  const int tid  = threadIdx.x;
  const int r    = tid >> 6;
  const int lane = tid & 63;
  const int row  = blockIdx.x * 4 + r;
  const int d0   = lane * 4;

  const vf4 v = *(const vf4*)(src + (size_t)row * 256 + d0);
  f16x4 hi, lo;
  #pragma unroll
  for (int j = 0; j < 4; ++j) {
    const float t = __fmul_rn(v[j], scale);
    const f16 h   = (f16)t;
    hi[j] = h;
    lo[j] = (f16)__fsub_rn(t, (float)h);
  }
  *(f16x4*)(dst + (size_t)row * 512 + d0)       = hi;
  *(f16x4*)(dst + (size_t)row * 512 + 256 + d0) = lo;
  *(vf4*)(&Xl[r][d0]) = v;
  __syncthreads();

  if (lane < 16) {
    const int h = lane >> 3, j = lane & 7;
    const float* a = &Xl[r][h * 128];
    float rv = __fmul_rn(a[j], a[j]);
    for (int i = 8; i < 128; i += 8)
      rv = __fadd_rn(rv, __fmul_rn(a[i + j], a[i + j]));
    scr[r][lane] = rv;
  }
  __syncthreads();
  if (lane == 0)
    sq[row] = __fadd_rn(np_comb8(&scr[r][0]), np_comb8(&scr[r][8]));
}

// ---------------------------------------------------------------------------
// MFMA candidate pass — ROUND-9 PROVEN CONFIG (560 us; 4 blocks/CU was a
// measured regression: FETCH 1.08->1.34 GB, dur 560->590). Grid: 2048 =
// 256 row-groups x 8 col-groups. Block = 128 rows x 512 cols (4 col-tiles
// of 128). Tile 128x128, 4 waves (2x2 of 64x64), BK=32. Virtual K = 768:
//   seg0: A off 0   B off 0    (hiX*hiE)
//   seg1: A off 256 B off 0    (loX*hiE)
//   seg2: A off 0   B off 256  (hiX*loE)
// TRIPLE-buffered stage LDS, COUNTED vmcnt (T3+T4): stage(st+2) issued at
// step st; gate = s_waitcnt vmcnt(4) + raw s_barrier + sched_barrier(0);
// st==23 drains. Buffer = st % 3; WAR-safe (last readers finished step-1).
// launch_bounds(256,3): cap 170 on unified VGPR+AGPR, 3 blocks/CU; LDS =
// 48K stage + 4K best = 53248 B, x3 = 159744 <= 160K.
// Running argmin top-2 in LDS per (row, wc-half), wave-owned (no barriers/
// atomics). Per-ct fold: thread 2-deep over fn, 16-lane butterfly, lc==0
// merges into LDS cell (ties keep stored = lower col = numpy first-index).
// Proxy t = fmaf(-two_scale, acc, e2[col]); exact argmin via recheck().
#define AOF(s) ((((s) >> 3) == 1 ? 256 : 0) + ((s) & 7) * 32)
#define BOF(s) ((((s) >> 3) == 2 ? 256 : 0) + ((s) & 7) * 32)
#define STAGE4(aP0, aP1, bP0, bP1, bufi)                                \
  do {                                                                  \
    GLD16((aP0), &As[(bufi)][wv * 1024]);                               \
    GLD16((aP1), &As[(bufi)][wv * 1024 + 512]);                         \
    GLD16((bP0), &Bs[(bufi)][wv * 1024]);                               \
    GLD16((bP1), &Bs[(bufi)][wv * 1024 + 512]);                         \
  } while (0)

__global__ __launch_bounds__(256, 3) void mfma_argmin(
    const f16* __restrict__ Xs, const f16* __restrict__ Es,
    const float* __restrict__ e2, const float two_scale,
    int* __restrict__ cand)
{
  __shared__ __align__(16) f16 As[3][128 * 32];
  __shared__ __align__(16) f16 Bs[3][128 * 32];
  __shared__ float bT[128][2][2];       // running top-2 value  [row][wc][rank]
  __shared__ int   bI[128][2][2];       // running top-2 index

  const int tid  = threadIdx.x;
  const int bid  = blockIdx.x;
  const int row0 = (bid >> 3) * 128;
  const int cg   = bid & 7;
  const int colbase = cg * 512;

  const int l  = tid & 63;
  const int wv = tid >> 6;
  const int wr = wv >> 1;
  const int wc = wv & 1;
  const int lc = l & 15;
  const int kc = l >> 4;

  // init wave-owned best cells (rows wr*64+l, col-half wc): no barrier needed
  bT[wr * 64 + l][wc][0] = INFINITY;  bT[wr * 64 + l][wc][1] = INFINITY;
  bI[wr * 64 + l][wc][0] = 0x7fffffff; bI[wr * 64 + l][wc][1] = 0x7fffffff;
  asm volatile("s_waitcnt lgkmcnt(0)" ::: "memory");

  // staging: wave wv stages rows [wv*32, wv*32+16) (issue0) and +16 (issue1)
  const int srow = wv * 32 + (l >> 2);
  const int chs  = (l & 3) ^ ((l >> 3) & 3);

  const f16* aB0 = Xs + (size_t)(row0 + srow) * 512 + chs * 8;
  const f16* aB1 = aB0 + 16 * 512;
  const f16* bBase0 = Es + (size_t)(colbase + srow) * 512 + chs * 8;
  const f16* bBase1 = bBase0 + 16 * 512;

  // frag-read swizzled k-slot (row = ..+lc; (row>>1)&3 == (lc>>1)&3)
  const int ks = (kc ^ ((lc >> 1) & 3)) * 8;

  const float nts = -two_scale;

  // prologue: stages 0 and 1 of ct=0 (8 loads in flight)
  STAGE4(aB0 + AOF(0), aB1 + AOF(0), bBase0 + BOF(0), bBase1 + BOF(0), 0);
  STAGE4(aB0 + AOF(1), aB1 + AOF(1), bBase0 + BOF(1), bBase1 + BOF(1), 1);

  #pragma unroll 1
  for (int ct = 0; ct < 4; ++ct) {
    const f16* bC0 = bBase0 + ct * 65536;   // + ct * 128 rows * 512 f16
    const f16* bC1 = bBase1 + ct * 65536;

    f32x4 acc[4][4];
    #pragma unroll
    for (int i = 0; i < 4; ++i)
      #pragma unroll
      for (int j = 0; j < 4; ++j)
        acc[i][j] = (f32x4){0.0f, 0.0f, 0.0f, 0.0f};

    #pragma unroll
    for (int st = 0; st < 24; ++st) {
      // gate: stage(st) complete everywhere; 4 newer loads stay in flight
      if (st == 23) { asm volatile("s_waitcnt vmcnt(0)" ::: "memory"); }
      else          { asm volatile("s_waitcnt vmcnt(4)" ::: "memory"); }
      __builtin_amdgcn_s_barrier();
      __builtin_amdgcn_sched_barrier(0);

      const int cur = st % 3;
      f16x8 af[4], bf[4];
      #pragma unroll
      for (int f = 0; f < 4; ++f) {
        af[f] = *(const f16x8*)(&As[cur][(wr * 64 + f * 16 + lc) * 32 + ks]);
        bf[f] = *(const f16x8*)(&Bs[cur][(wc * 64 + f * 16 + lc) * 32 + ks]);
      }

      // issue stage(st+2) into buf (st+2)%3 (last read at step st-1: WAR-safe)
      if (st + 2 < 24) {
        STAGE4(aB0 + AOF(st + 2), aB1 + AOF(st + 2),
               bC0 + BOF(st + 2), bC1 + BOF(st + 2), (st + 2) % 3);
      } else if (ct < 3) {                  // seam: next ct's stage st-22
        STAGE4(aB0 + AOF(st - 22), aB1 + AOF(st - 22),
               bC0 + 65536 + BOF(st - 22), bC1 + 65536 + BOF(st - 22),
               (st + 2) % 3);
      }

      __builtin_amdgcn_s_setprio(1);
      #pragma unroll
      for (int fm = 0; fm < 4; ++fm)
        #pragma unroll
        for (int fn = 0; fn < 4; ++fn)
          acc[fm][fn] = __builtin_amdgcn_mfma_f32_16x16x32_f16(
              af[fm], bf[fn], acc[fm][fn], 0, 0, 0);
      __builtin_amdgcn_s_setprio(0);
    }

    // ---- per-ct fold: thread 2-deep -> 16-lane butterfly -> LDS merge ----
    float e2v[4];
    #pragma unroll
    for (int fn = 0; fn < 4; ++fn)
      e2v[fn] = e2[colbase + ct * 128 + wc * 64 + fn * 16 + lc];

    #pragma unroll
    for (int fm = 0; fm < 4; ++fm) {
      #pragma unroll
      for (int j = 0; j < 4; ++j) {
        float u1 = INFINITY, u2 = INFINITY;
        int   v1 = 0x7fffffff, v2 = 0x7fffffff;
        #pragma unroll
        for (int fn = 0; fn < 4; ++fn) {
          const int col = colbase + ct * 128 + wc * 64 + fn * 16 + lc;
          const float t = fmaf(nts, acc[fm][fn][j], e2v[fn]);
          if (t < u1) { u2 = u1; v2 = v1; u1 = t; v1 = col; }
          else if (t < u2) { u2 = t; v2 = col; }
        }
        // butterfly over the 16 lc lanes (all lanes converge)
        #pragma unroll
        for (int m = 1; m < 16; m <<= 1) {
          const float p1 = __shfl_xor(u1, m);
          const float p2 = __shfl_xor(u2, m);
          const int   q1 = __shfl_xor(v1, m);
          const int   q2 = __shfl_xor(v2, m);
          const bool pl = (p1 < u1) || (p1 == u1 && q1 < v1);
          float n1, n2; int m1, m2;
          if (pl) {
            n1 = p1; m1 = q1;
            const bool sl = (u1 < p2) || (u1 == p2 && v1 < q2);
            n2 = sl ? u1 : p2; m2 = sl ? v1 : q2;
          } else {
            n1 = u1; m1 = v1;
            const bool sl = (p1 < u2) || (p1 == u2 && q1 < v2);
            n2 = sl ? p1 : u2; m2 = sl ? q1 : v2;
          }
          u1 = n1; v1 = m1; u2 = n2; v2 = m2;
        }
        if (lc == 0) {                       // merge into wave-owned LDS cell
          const int rloc = wr * 64 + fm * 16 + kc * 4 + j;
          const float c1 = bT[rloc][wc][0], c2 = bT[rloc][wc][1];
          const int   d1 = bI[rloc][wc][0], d2 = bI[rloc][wc][1];
          const bool fn_ = (u1 < c1) || (u1 == c1 && v1 < d1);
          float r1, r2; int s1, s2;
          if (fn_) {
            r1 = u1; s1 = v1;
            const bool sl = (u2 < c1) || (u2 == c1 && v2 < d1);
            r2 = sl ? u2 : c1; s2 = sl ? v2 : d1;
          } else {
            r1 = c1; s1 = d1;
            const bool sl = (c2 < u1) || (c2 == u1 && d2 < v1);
            r2 = sl ? c2 : u1; s2 = sl ? d2 : v1;
          }
          bT[rloc][wc][0] = r1; bT[rloc][wc][1] = r2;
          bI[rloc][wc][0] = s1; bI[rloc][wc][1] = s2;
        }
      }
    }
  }

  // final: all waves' merges visible, write 4 candidates per row
  __syncthreads();
  if (tid < 128) {
    const size_t base = ((size_t)(row0 + tid) * 8 + cg) * 4;
    cand[base]     = bI[tid][0][0];
    cand[base + 1] = bI[tid][0][1];
    cand[base + 2] = bI[tid][1][0];
    cand[base + 3] = bI[tid][1][1];
  }
}

// ---------------------------------------------------------------------------
// exact recheck: for each row, recompute numpy-exact f32 distance for the 32
// candidates and take lexicographic (s, k) min — identical arithmetic to the
// previously-passing VALU kernel (serial ascending-d fmaf chain, then
// s = fl(fl(x2 - fl(2*acc)) + e2[k])), numpy first-index tie semantics.
__global__ void recheck(const float* __restrict__ X, const float* __restrict__ x2g,
                        const float* __restrict__ Eref, const float* __restrict__ e2ref,
                        const int* __restrict__ cand, int* __restrict__ idxo)
{
  __shared__ float Xl[8][256];
  const int tid  = threadIdx.x;
  const int rg   = tid >> 5;            // row within block (8 rows/block)
  const int lr   = tid & 31;            // candidate lane
  const int row0 = blockIdx.x * 8;
  const int row  = row0 + rg;

  {
    const float* xp = X + (size_t)row * 256 + lr * 8;
    *(vf4*)(&Xl[rg][lr * 8])     = *(const vf4*)xp;
    *(vf4*)(&Xl[rg][lr * 8 + 4]) = *(const vf4*)(xp + 4);
  }
  __syncthreads();

  int k = cand[(size_t)row * 32 + lr];

  float acc = 0.0f;
  const float* ep = Eref + (size_t)k * 256;
  for (int d4 = 0; d4 < 64; ++d4) {
    const vf4 xv = *(const vf4*)(&Xl[rg][d4 * 4]);
    const vf4 ev = *(const vf4*)(ep + d4 * 4);
    acc = fmaf(xv[0], ev[0], acc);
    acc = fmaf(xv[1], ev[1], acc);
    acc = fmaf(xv[2], ev[2], acc);
    acc = fmaf(xv[3], ev[3], acc);
  }
  float s = __fadd_rn(__fsub_rn(x2g[row], __fmul_rn(2.0f, acc)), e2ref[k]);

  #pragma unroll
  for (int m = 1; m < 32; m <<= 1) {
    const float os = __shfl_xor(s, m);
    const int   ok = __shfl_xor(k, m);
    if (os < s || (os == s && ok < k)) { s = os; k = ok; }
  }
  if (lr == 0) idxo[row] = k;
}

// ----------------------- counts + dw atomics + loss (no OQ/OI writes) ------
__global__ void stats_cd(const float* __restrict__ X, const float* __restrict__ E,
                         const int* __restrict__ idx, float* __restrict__ counts,
                         float* __restrict__ dw, double* __restrict__ loss_acc)
{
  __shared__ double part[4];
  const int tid  = threadIdx.x;
  const int lane = tid & 63, w = tid >> 6;
  const int row  = blockIdx.x * 4 + w;
  const int k    = idx[row];
  const vf4 xv = ((const vf4*)X)[(size_t)row * 64 + lane];
  const vf4 qv = ((const vf4*)E)[(size_t)k * 64 + lane];
  const float d0 = xv[0]-qv[0], d1 = xv[1]-qv[1], d2 = xv[2]-qv[2], d3 = xv[3]-qv[3];
  double ps = (double)(d0*d0 + d1*d1 + d2*d2 + d3*d3);
  #pragma unroll
  for (int o = 32; o; o >>= 1) ps += __shfl_down(ps, o);
  #pragma unroll
  for (int j = 0; j < 4; ++j)
    atomicAdd(dw + (size_t)k * Dim + lane * 4 + j, xv[j]);
  if (lane == 0) {
    part[w] = ps;
    atomicAdd(counts + k, 1.0f);
  }
  __syncthreads();
  if (tid == 0) atomicAdd(loss_acc, part[0] + part[1] + part[2] + part[3]);
}

// quantized gather + index write, LAST (frees OQ region for Xs during argmins)
__global__ void gather_q(const float* __restrict__ E, const int* __restrict__ idx,
                         float* __restrict__ out)
{
  const int tid  = threadIdx.x;
  const int lane = tid & 63, w = tid >> 6;
  const int row  = blockIdx.x * 4 + w;
  const int k    = idx[row];
  ((vf4*)out)[(size_t)row * 64 + lane] = ((const vf4*)E)[(size_t)k * 64 + lane];
  if (lane == 0) out[OI + row] = (float)k;
}

// ------------------------------------------------- per-code EMA scalar updates
__global__ void cs_usage(const float* __restrict__ ecs, const float* __restrict__ usage,
                         const float* __restrict__ counts, float* __restrict__ out,
                         int* __restrict__ pos_cnt)
{
  __shared__ int si[256];
  const int tid = threadIdx.x;
  const int k   = blockIdx.x * 256 + tid;
  const float cnt = counts[k];
  const float ncs = __fadd_rn(__fmul_rn(ecs[k], 0.99f), __fmul_rn(0.01f, cnt));
  out[OCS + k] = ncs;
  const float nus = __fadd_rn(__fmul_rn(usage[k], 0.99f), __fmul_rn(0.01f, cnt));
  out[OU + k] = nus;
  si[tid] = (nus > 0.0f) ? 1 : 0;
  __syncthreads();
  for (int s = 128; s; s >>= 1) {
    if (tid < s) si[tid] += si[tid + s];
    __syncthreads();
  }
  if (tid == 0) atomicAdd(pos_cnt, si[0]);
}

// n = np.sum(new_cs), numpy pairwise over 4096
__global__ void n_np_kernel(const float* __restrict__ ncs, float* __restrict__ nf) {
  __shared__ float leaf[32];
  const int t = threadIdx.x;
  if (t < 32) {
    const float* a = ncs + t * 128;
    float r[8];
    #pragma unroll
    for (int j = 0; j < 8; ++j) r[j] = a[j];
    for (int i = 8; i < 128; i += 8)
      #pragma unroll
      for (int j = 0; j < 8; ++j) r[j] = __fadd_rn(r[j], a[i + j]);
    leaf[t] = np_comb8(r);
  }
  __syncthreads();
  if (t == 0) {
    float v[32];
    #pragma unroll
    for (int i = 0; i < 32; ++i) v[i] = leaf[i];
    for (int n = 32; n > 1; n >>= 1)
      for (int i = 0; i < (n >> 1); ++i) v[i] = __fadd_rn(v[2 * i], v[2 * i + 1]);
    *nf = v[0];
  }
}

// ---------------------------------------------------------------------------
// FUSED emb_pre + rowsq(pre) + split(pre). Block per code k, 256 threads.
// Computes new_ema_w (in place over dw accum) and pre-embedding p (numpy-f32
// op order, written to out[OE]; all consumers run pre-reset), stages p in
// LDS, computes e2p via the np_sq256-exact 16-chain tree, and limb-splits p
// into Es directly (no global re-read of pre).
__global__ void emb_fused(const float* __restrict__ emaw, float* __restrict__ out,
                          const float* __restrict__ nf, f16* __restrict__ Es,
                          float* __restrict__ e2p)
{
  __shared__ float Pl[256];
  __shared__ float scr[16];
  const int k = blockIdx.x;
  const int d = threadIdx.x;
  const size_t o = (size_t)k * Dim + d;
  const float dwv = out[OW + o];
  const float w = __fadd_rn(__fmul_rn(emaw[o], 0.99f), __fmul_rn(0.01f, dwv));
  out[OW + o] = w;
  const float nv  = *nf;
  const float ncs = out[OCS + k];
  const float cs  = __fmul_rn(__fdiv_rn(__fadd_rn(ncs, EPSf), __fadd_rn(nv, KEPSf)), nv);
  const float p = __fdiv_rn(w, cs);
  out[OE + o] = p;
  Pl[d] = p;

  // limb split, scale 2^8 (exact): hi = f16(p*256); lo = f16(fl(t - hi))
  const float t = __fmul_rn(p, 256.0f);
  const f16 h = (f16)t;
  Es[(size_t)k * 512 + d]       = h;
  Es[(size_t)k * 512 + 256 + d] = (f16)__fsub_rn(t, (float)h);

  __syncthreads();
  if (d < 16) {
    const int hh = d >> 3, j = d & 7;
    const float* a = &Pl[hh * 128];
    float rv = __fmul_rn(a[j], a[j]);
    for (int i = 8; i < 128; i += 8)
      rv = __fadd_rn(rv, __fmul_rn(a[i + j], a[i + j]));
    scr[d] = rv;
  }
  __syncthreads();
  if (d == 0)
    e2p[k] = __fadd_rn(np_comb8(&scr[0]), np_comb8(&scr[8]));
}

__global__ void used_scatter(const int* __restrict__ idx2, int* __restrict__ used) {
  const int i = blockIdx.x * 256 + threadIdx.x;
  used[idx2[i]] = 1;
}

__global__ void finalize_k(const float* __restrict__ X, const int* __restrict__ used,
                           const int* __restrict__ steps_in, const int* __restrict__ rnd,
                           float* __restrict__ out)
{
  const int k = blockIdx.x, d = threadIdx.x;
  const int u = used[k];
  const float st = u ? 0.0f : (float)steps_in[k] + 1.0f;
  const bool dead = st > 100.0f;
  if (dead) out[OE + (size_t)k * Dim + d] = X[(size_t)rnd[k] * Dim + d];
  if (d == 0) out[OS + k] = dead ? 0.0f : st;
}

__global__ void write_scalars(const double* __restrict__ loss_acc,
                              const int* __restrict__ pos_cnt, float* __restrict__ out)
{
  if (threadIdx.x == 0) {
    out[OL] = 0.25f * (float)(*loss_acc / (double)((size_t)Ncnt * Dim));
    out[OR] = (float)(*pos_cnt) / (float)Kcb;
  }
}

// ---------------------------------------------------------------------- launch
extern "C" void kernel_launch(void* const* d_in, const int* in_sizes, int n_in,
                              void* d_out, int out_size, void* d_ws, size_t ws_size,
                              hipStream_t stream)
{
  const float* X     = (const float*)d_in[0];
  const float* E     = (const float*)d_in[1];
  const float* ECS   = (const float*)d_in[2];
  const float* EMAW  = (const float*)d_in[3];
  const float* USAGE = (const float*)d_in[4];
  const int*   STEPS = (const int*)d_in[5];
  const int*   RND   = (const int*)d_in[6];
  float* out = (float*)d_out;

  float* wsf = (float*)d_ws;
  float*  counts   = wsf;                          // [4096]  zeroed
  int*    used     = (int*)(wsf + 4096);           // [4096]  zeroed
  double* loss_acc = (double*)(wsf + 8192);        //         zeroed
  float*  nf       = wsf + 8194;
  int*    pos_cnt  = (int*)(wsf + 8195);
  const size_t ZN  = 8200;                         // zero region, floats
  float* x2g  = wsf + 8320;                        // [32768]          -> 41088
  float* e2   = wsf + 41088;                       // [4096]           -> 45184
  float* e2p  = wsf + 45184;                       // [4096]           -> 49280
  int*   idx1 = (int*)(wsf + 49280);               // [32768]          -> 82048
  int*   idx2 = (int*)(wsf + 82048);               // [32768]          -> 114816
  f16*   Es   = (f16*)(wsf + 114816);              // 4096*512 f16 = 1048576 f -> 1163392
  int*   cand = (int*)(wsf + 1163392);             // 32768*32 ints    -> 2211968
  // pre-reset embedding lives directly in out[OE] (consumers run pre-reset).
  // Xs (32768x512 f16 = 32 MiB) parks exactly in the OQ output region;
  // gather_q rewrites OQ after the second argmin is done.
  f16*   Xsp  = (f16*)out;

  hipMemsetAsync(d_ws, 0, ZN * sizeof(float), stream);
  hipMemsetAsync(out + OW, 0, (size_t)Kcb * Dim * sizeof(float), stream); // dw accum

  rs_fused     <<<Ncnt / 4, 256, 0, stream>>>(X, Xsp, 64.0f, x2g);         // 2^6
  rs_fused     <<<Kcb / 4,  256, 0, stream>>>(E, Es, 16777216.0f, e2);     // 2^24
  mfma_argmin  <<<2048,     256, 0, stream>>>(Xsp, Es, e2, 0x1p-29f, cand);
  recheck      <<<Ncnt / 8, 256, 0, stream>>>(X, x2g, E, e2, cand, idx1);
  stats_cd     <<<Ncnt / 4, 256, 0, stream>>>(X, E, idx1, counts, out + OW, loss_acc);
  cs_usage     <<<Kcb / 256, 256, 0, stream>>>(ECS, USAGE, counts, out, pos_cnt);
  n_np_kernel  <<<1,        64,  0, stream>>>(out + OCS, nf);
  emb_fused    <<<Kcb,      256, 0, stream>>>(EMAW, out, nf, Es, e2p);     // 2^8
  mfma_argmin  <<<2048,     256, 0, stream>>>(Xsp, Es, e2p, 0x1p-13f, cand);
  recheck      <<<Ncnt / 8, 256, 0, stream>>>(X, x2g, out + OE, e2p, cand, idx2);
  used_scatter <<<Ncnt / 256, 256, 0, stream>>>(idx2, used);
  finalize_k   <<<Kcb,      256, 0, stream>>>(X, used, STEPS, RND, out);
  gather_q     <<<Ncnt / 4, 256, 0, stream>>>(E, idx1, out);
  write_scalars<<<1,        64,  0, stream>>>(loss_acc, pos_cnt, out);

  (void)in_sizes; (void)n_in; (void)out_size; (void)ws_size;
}